// Round 2
// baseline (556.056 us; speedup 1.0000x reference)
//
#include <hip/hip_runtime.h>
#include <hip/hip_bf16.h>

#define NTOK 4096
#define DDIM 1024
#define NEXP 8
#define FDIM 4096
#define MAXTILES 40

typedef __attribute__((ext_vector_type(4))) float f32x4;
typedef __attribute__((ext_vector_type(8))) short bf16x8;
typedef __attribute__((ext_vector_type(8))) unsigned short u16x8;

#define GLDS(g, l) __builtin_amdgcn_global_load_lds( \
    (const __attribute__((address_space(1))) unsigned int*)(g), \
    (__attribute__((address_space(3))) unsigned int*)(l), 16, 0, 0)

// ---------------- route: no global atomics. Writes xs (bf16), amax[], partial[256][16] ----
__global__ __launch_bounds__(256) void route_kernel(
    const float* __restrict__ x,         // [NTOK, D]
    const float* __restrict__ w_switch,  // [D, E]
    const float* __restrict__ b_switch,  // [E]
    __hip_bfloat16* __restrict__ xs,     // [NTOK, D]
    int* __restrict__ amax_arr,          // [NTOK]
    float* __restrict__ partial)         // [256][16]: 0..7 prob sums, 8..15 counts
{
    const int tid = threadIdx.x;
    const int wave = tid >> 6, lane = tid & 63;
    __shared__ float pr[4][16];

    float wacc[16];
#pragma unroll
    for (int j = 0; j < 16; j++) wacc[j] = 0.0f;

    for (int i = 0; i < 4; i++) {
        const int n = blockIdx.x * 16 + wave * 4 + i;
        const float4* xr = (const float4*)(x + (size_t)n * DDIM);
        float4 xv[4];
#pragma unroll
        for (int j = 0; j < 4; j++) xv[j] = xr[lane + j * 64];

        float acc[NEXP];
#pragma unroll
        for (int e = 0; e < NEXP; e++) acc[e] = 0.0f;
#pragma unroll
        for (int j = 0; j < 4; j++) {
            const int dbase = (lane + j * 64) * 4;
#pragma unroll
            for (int c = 0; c < 4; c++) {
                const float4* wr = (const float4*)(w_switch + (size_t)(dbase + c) * NEXP);
                float4 w0 = wr[0], w1 = wr[1];
                float xvc = ((const float*)&xv[j])[c];
                acc[0] += xvc * w0.x; acc[1] += xvc * w0.y;
                acc[2] += xvc * w0.z; acc[3] += xvc * w0.w;
                acc[4] += xvc * w1.x; acc[5] += xvc * w1.y;
                acc[6] += xvc * w1.z; acc[7] += xvc * w1.w;
            }
        }
#pragma unroll
        for (int e = 0; e < NEXP; e++) {
            float v = acc[e];
#pragma unroll
            for (int off = 32; off > 0; off >>= 1) v += __shfl_xor(v, off, 64);
            acc[e] = v;
        }
        float mx = -1e30f;
#pragma unroll
        for (int e = 0; e < NEXP; e++) {
            acc[e] += b_switch[e];
            mx = fmaxf(mx, acc[e]);
        }
        float sum = 0.0f;
#pragma unroll
        for (int e = 0; e < NEXP; e++) { acc[e] = __expf(acc[e] - mx); sum += acc[e]; }
        float inv = 1.0f / sum;
        float pmax = -1.0f; int amax = 0;
#pragma unroll
        for (int e = 0; e < NEXP; e++) {
            float p = acc[e] * inv;
            acc[e] = p;
            if (p > pmax) { pmax = p; amax = e; }
        }
#pragma unroll
        for (int e = 0; e < NEXP; e++) {
            wacc[e] += acc[e];
            wacc[8 + e] += (amax == e) ? 1.0f : 0.0f;
        }
        if (lane == 0) amax_arr[n] = amax;
#pragma unroll
        for (int j = 0; j < 4; j++) {
            ushort4 pk;
            __hip_bfloat16* pp = (__hip_bfloat16*)&pk;
            pp[0] = __float2bfloat16(xv[j].x * pmax);
            pp[1] = __float2bfloat16(xv[j].y * pmax);
            pp[2] = __float2bfloat16(xv[j].z * pmax);
            pp[3] = __float2bfloat16(xv[j].w * pmax);
            *(ushort4*)(xs + (size_t)n * DDIM + (lane + j * 64) * 4) = pk;
        }
    }
    if (lane == 0) {
#pragma unroll
        for (int j = 0; j < 16; j++) pr[wave][j] = wacc[j];
    }
    __syncthreads();
    if (tid < 16)
        partial[blockIdx.x * 16 + tid] = pr[0][tid] + pr[1][tid] + pr[2][tid] + pr[3][tid];
}

// ---------------- bucket: per-expert token lists, ballot-aggregated, LDS counter ----------
__global__ __launch_bounds__(1024) void bucket_kernel(
    const int* __restrict__ amax_arr, int* __restrict__ bucket, int* __restrict__ ecnt)
{
    const int e = blockIdx.x;
    __shared__ int ctr;
    if (threadIdx.x == 0) ctr = 0;
    __syncthreads();
    const int lane = threadIdx.x & 63;
    for (int c = 0; c < NTOK; c += 1024) {
        int t = c + threadIdx.x;
        bool my = (amax_arr[t] == e);
        unsigned long long mask = __ballot(my);
        int cnt = __popcll(mask);
        int base = 0;
        if (lane == 0 && cnt) base = atomicAdd(&ctr, cnt);
        base = __shfl(base, 0, 64);
        if (my) {
            int rank = __popcll(mask & ((1ull << lane) - 1ull));
            bucket[e * NTOK + base + rank] = t;
        }
    }
    __syncthreads();
    if (threadIdx.x == 0) ecnt[e] = ctr;
}

// ---------------- finalize + m-tile table ----------------
__global__ __launch_bounds__(256) void finalize_table_kernel(
    const float* __restrict__ partial, const int* __restrict__ ecnt,
    float* __restrict__ out_tail, int* __restrict__ table)
{
    __shared__ float red[16][16];
    const int j = threadIdx.x & 15, g = threadIdx.x >> 4;
    float s = 0.0f;
    for (int k = 0; k < 16; k++) s += partial[(size_t)(g + k * 16) * 16 + j];
    red[g][j] = s;
    __syncthreads();
    if (threadIdx.x < 16) {
        float t = 0.0f;
        for (int k = 0; k < 16; k++) t += red[k][threadIdx.x];
        int dst = (threadIdx.x < 8) ? (8 + threadIdx.x) : (threadIdx.x - 8);
        out_tail[dst] = t;
    }
    if (threadIdx.x == 16) out_tail[16] = 0.0f;  // n_dropped
    if (threadIdx.x == 0) {
        int idx = 0;
        for (int e = 0; e < NEXP; e++) {
            int cnt = ecnt[e];
            for (int m0 = 0; m0 < cnt; m0 += 128) table[idx++] = (e << 16) | m0;
        }
        for (; idx < MAXTILES; idx++) table[idx] = -1;
    }
}

// ---------------- init_out: out[t][:] = b2[amax[t]][:] (bias pre-fill for atomic GEMM2) ----
__global__ __launch_bounds__(256) void init_out_kernel(
    const float* __restrict__ b2, const int* __restrict__ amax_arr,
    float* __restrict__ out)
{
    const int t = blockIdx.x;
    const int e = amax_arr[t];
    const float4* br = (const float4*)(b2 + (size_t)e * DDIM);
    ((float4*)(out + (size_t)t * DDIM))[threadIdx.x] = br[threadIdx.x];
}

// ---------------- transpose+convert: fp32 [E,R,C] -> bf16 [E,C,R] ----------------
template <int R, int C>
__global__ __launch_bounds__(256) void transpose_kernel(
    const float* __restrict__ in, __hip_bfloat16* __restrict__ outp)
{
    const int e = blockIdx.z;
    const int r0 = blockIdx.y * 64, c0 = blockIdx.x * 64;
    __shared__ __hip_bfloat16 t[64 * 65];
    const int tid = threadIdx.x;
    const int ri = tid >> 4, c4 = (tid & 15) * 4;
    const float* src = in + ((size_t)e * R + r0) * C + c0;
#pragma unroll
    for (int rr = 0; rr < 4; rr++) {
        int r = ri + rr * 16;
        float4 v = *(const float4*)(src + (size_t)r * C + c4);
        t[r * 65 + c4 + 0] = __float2bfloat16(v.x);
        t[r * 65 + c4 + 1] = __float2bfloat16(v.y);
        t[r * 65 + c4 + 2] = __float2bfloat16(v.z);
        t[r * 65 + c4 + 3] = __float2bfloat16(v.w);
    }
    __syncthreads();
    const int co = tid >> 2, m = tid & 3;
    u16x8 v0, v1;
#pragma unroll
    for (int idx = 0; idx < 8; idx++)
        ((unsigned short*)&v0)[idx] = *(const unsigned short*)&t[(m * 16 + idx) * 65 + co];
#pragma unroll
    for (int idx = 0; idx < 8; idx++)
        ((unsigned short*)&v1)[idx] = *(const unsigned short*)&t[(m * 16 + idx + 8) * 65 + co];
    __hip_bfloat16* dst = outp + ((size_t)e * C + c0 + co) * R + r0 + m * 16;
    *(u16x8*)(dst) = v0;
    *(u16x8*)(dst + 8) = v1;
}

// ---------------- grouped GEMM body: 128x128 tile, BK=32, DEPTH-2 counted-vmcnt pipeline --
// T3+T4: 3 LDS buffers; at iteration t stage tile t+2, compute tile t, then wait vmcnt(4)
// (= tile t+1's 4 loads, the oldest outstanding) and barrier. Loads get ~2 full iterations
// in flight; never drain vmcnt to 0 in steady state.
// MODE 0: h = bf16(relu(acc + bias)), KS=1.   MODE 1: unsafeAtomicAdd fp32 (bias pre-filled).
template <int MODE, int K, int NN, int KS>
__device__ __forceinline__ void gemm_body(
    const __hip_bfloat16* __restrict__ A,
    const __hip_bfloat16* __restrict__ Bt,
    const float* __restrict__ bias,
    const int* __restrict__ bucket,
    const int* __restrict__ ecnt,
    const int* __restrict__ table,
    void* __restrict__ Out)
{
    const int entry = table[blockIdx.y];
    if (entry < 0) return;
    const int e = entry >> 16;
    const int m0 = entry & 0xffff;
    const int cnt = ecnt[e];
    const int n0 = blockIdx.x * 128;
    const int kbase = (K / KS) * blockIdx.z;

    __shared__ __align__(16) __hip_bfloat16 Asm[3][128 * 32];  // 3 x 8 KB
    __shared__ __align__(16) __hip_bfloat16 Bsm[3][128 * 32];  // 3 x 8 KB
    __shared__ int toks[128];

    const int tid = threadIdx.x;
    if (tid < 128) {
        int r = m0 + tid;
        toks[tid] = bucket[e * NTOK + (r < cnt ? r : cnt - 1)];
    }
    __syncthreads();

    const int wave = tid >> 6, lane = tid & 63;
    const int r = lane & 15, kq = lane >> 4;
    const int g0 = 2 * wave;

    const __hip_bfloat16* pA0 = A + (size_t)toks[g0 * 16 + r] * K + kbase + kq * 8;
    const __hip_bfloat16* pA1 = A + (size_t)toks[(g0 + 1) * 16 + r] * K + kbase + kq * 8;
    const __hip_bfloat16* pB0 = Bt + ((size_t)e * NN + n0 + g0 * 16 + r) * K + kbase + kq * 8;
    const __hip_bfloat16* pB1 = Bt + ((size_t)e * NN + n0 + (g0 + 1) * 16 + r) * K + kbase + kq * 8;

    const int wm = wave & 1, wn = wave >> 1;
    f32x4 acc[4][4];
#pragma unroll
    for (int t = 0; t < 4; t++)
#pragma unroll
        for (int u = 0; u < 4; u++) acc[t][u] = (f32x4){0.f, 0.f, 0.f, 0.f};

    constexpr int NSTEP = (K / KS) / 32;
    static_assert(NSTEP >= 2, "pipeline needs >=2 K-steps");

    auto stage = [&](int b) {
        char* la = (char*)Asm + b * 8192 + g0 * 1024;
        char* lb = (char*)Bsm + b * 8192 + g0 * 1024;
        GLDS(pA0, la); GLDS(pA1, la + 1024);
        GLDS(pB0, lb); GLDS(pB1, lb + 1024);
        pA0 += 32; pA1 += 32; pB0 += 32; pB1 += 32;
    };

    // prologue: tiles 0 and 1 in flight; wait only for tile 0 (oldest 4 of 8)
    stage(0);
    stage(1);
    asm volatile("s_waitcnt vmcnt(4)" ::: "memory");
    __builtin_amdgcn_s_barrier();

    for (int t = 0; t < NSTEP; ++t) {
        const int cb = t % 3;
        if (t + 2 < NSTEP) stage((t + 2) % 3);

        const char* Ab = (const char*)Asm + cb * 8192;
        const char* Bb = (const char*)Bsm + cb * 8192;
        bf16x8 a[4], b[4];
#pragma unroll
        for (int t4 = 0; t4 < 4; t4++)
            a[t4] = *(const bf16x8*)(Ab + (wm * 4 + t4) * 1024 + lane * 16);
#pragma unroll
        for (int u = 0; u < 4; u++)
            b[u] = *(const bf16x8*)(Bb + (wn * 4 + u) * 1024 + lane * 16);
#pragma unroll
        for (int t4 = 0; t4 < 4; t4++)
#pragma unroll
            for (int u = 0; u < 4; u++)
                acc[t4][u] = __builtin_amdgcn_mfma_f32_16x16x32_bf16(a[t4], b[u], acc[t4][u], 0, 0, 0);

        if (t + 2 < NSTEP) {
            // tile t+1 (oldest 4 of 8 outstanding) must have landed; t+2 stays in flight
            asm volatile("s_waitcnt vmcnt(4)" ::: "memory");
            __builtin_amdgcn_s_barrier();
        } else if (t + 1 < NSTEP) {
            asm volatile("s_waitcnt vmcnt(0)" ::: "memory");
            __builtin_amdgcn_s_barrier();
        }
    }

    const int quad = lane >> 4, l15 = lane & 15;
    float bv[4];
#pragma unroll
    for (int u = 0; u < 4; u++)
        bv[u] = (MODE == 0) ? bias[(size_t)e * NN + n0 + wn * 64 + u * 16 + l15] : 0.0f;
#pragma unroll
    for (int t = 0; t < 4; t++) {
#pragma unroll
        for (int rr = 0; rr < 4; rr++) {
            int row = wm * 64 + t * 16 + quad * 4 + rr;
            if (m0 + row < cnt) {
                int tok = toks[row];
#pragma unroll
                for (int u = 0; u < 4; u++) {
                    int col = n0 + wn * 64 + u * 16 + l15;
                    float v = acc[t][u][rr] + bv[u];
                    if (MODE == 0) {
                        v = fmaxf(v, 0.0f);
                        ((__hip_bfloat16*)Out)[(size_t)tok * NN + col] = __float2bfloat16(v);
                    } else {
                        unsafeAtomicAdd(&((float*)Out)[(size_t)tok * NN + col], v);
                    }
                }
            }
        }
    }
}

__global__ __launch_bounds__(256) void gemm_ffn1(
    const __hip_bfloat16* __restrict__ A, const __hip_bfloat16* __restrict__ Bt,
    const float* __restrict__ bias, const int* __restrict__ bucket,
    const int* __restrict__ ecnt, const int* __restrict__ table, void* __restrict__ Out)
{
    gemm_body<0, DDIM, FDIM, 1>(A, Bt, bias, bucket, ecnt, table, Out);
}

__global__ __launch_bounds__(256) void gemm_ffn2(
    const __hip_bfloat16* __restrict__ A, const __hip_bfloat16* __restrict__ Bt,
    const float* __restrict__ bias, const int* __restrict__ bucket,
    const int* __restrict__ ecnt, const int* __restrict__ table, void* __restrict__ Out)
{
    gemm_body<1, FDIM, DDIM, 4>(A, Bt, bias, bucket, ecnt, table, Out);
}

extern "C" void kernel_launch(void* const* d_in, const int* in_sizes, int n_in,
                              void* d_out, int out_size, void* d_ws, size_t ws_size,
                              hipStream_t stream) {
    const float* x        = (const float*)d_in[0];
    const float* w_switch = (const float*)d_in[1];
    const float* b_switch = (const float*)d_in[2];
    const float* w1       = (const float*)d_in[3];
    const float* b1       = (const float*)d_in[4];
    const float* w2       = (const float*)d_in[5];
    const float* b2       = (const float*)d_in[6];

    float* out = (float*)d_out;
    float* out_tail = out + (size_t)NTOK * DDIM;

    char* ws = (char*)d_ws;
    __hip_bfloat16* xs = (__hip_bfloat16*)(ws);                        // 8 MB
    __hip_bfloat16* h  = (__hip_bfloat16*)(ws + 8388608ull);           // 32 MB
    __hip_bfloat16* wt = (__hip_bfloat16*)(ws + 41943040ull);          // 64 MB (shared w1t/w2t)
    int* bucket        = (int*)(ws + 109051904ull);                    // 128 KB
    int* amax_arr      = (int*)(ws + 109182976ull);                    // 16 KB
    float* partial     = (float*)(ws + 109199360ull);                  // 16 KB
    int* ecnt          = (int*)(ws + 109215744ull);                    // 32 B
    int* table         = (int*)(ws + 109215776ull);                    // 160 B

    hipLaunchKernelGGL(route_kernel, dim3(256), dim3(256), 0, stream,
                       x, w_switch, b_switch, xs, amax_arr, partial);
    hipLaunchKernelGGL(bucket_kernel, dim3(NEXP), dim3(1024), 0, stream,
                       amax_arr, bucket, ecnt);
    hipLaunchKernelGGL(finalize_table_kernel, dim3(1), dim3(256), 0, stream,
                       partial, ecnt, out_tail, table);
    hipLaunchKernelGGL(init_out_kernel, dim3(NTOK), dim3(256), 0, stream,
                       b2, amax_arr, out);

    // w1 [E,1024,4096] -> w1t [E,4096,1024]
    hipLaunchKernelGGL((transpose_kernel<DDIM, FDIM>), dim3(FDIM / 64, DDIM / 64, NEXP),
                       dim3(256), 0, stream, w1, wt);
    hipLaunchKernelGGL(gemm_ffn1, dim3(FDIM / 128, MAXTILES), dim3(256), 0, stream,
                       xs, wt, b1, bucket, ecnt, table, (void*)h);

    // w2 [E,4096,1024] -> w2t [E,1024,4096]  (reuses wt after gemm1)
    hipLaunchKernelGGL((transpose_kernel<FDIM, DDIM>), dim3(DDIM / 64, FDIM / 64, NEXP),
                       dim3(256), 0, stream, w2, wt);
    hipLaunchKernelGGL(gemm_ffn2, dim3(DDIM / 128, MAXTILES, 4), dim3(256), 0, stream,
                       h, wt, b2, bucket, ecnt, table, (void*)out);
}

// Round 3
// 515.255 us; speedup vs baseline: 1.0792x; 1.0792x over previous
//
#include <hip/hip_runtime.h>
#include <hip/hip_bf16.h>

#define NTOK 4096
#define DDIM 1024
#define NEXP 8
#define FDIM 4096
#define MAXTILES 40

typedef __attribute__((ext_vector_type(4))) float f32x4;
typedef __attribute__((ext_vector_type(8))) short bf16x8;
typedef __attribute__((ext_vector_type(8))) unsigned short u16x8;

#define GLDS(g, l) __builtin_amdgcn_global_load_lds( \
    (const __attribute__((address_space(1))) unsigned int*)(g), \
    (__attribute__((address_space(3))) unsigned int*)(l), 16, 0, 0)

// ---------------- route: no global atomics. Writes xs (bf16), amax[], partial[256][16] ----
__global__ __launch_bounds__(256) void route_kernel(
    const float* __restrict__ x,         // [NTOK, D]
    const float* __restrict__ w_switch,  // [D, E]
    const float* __restrict__ b_switch,  // [E]
    __hip_bfloat16* __restrict__ xs,     // [NTOK, D]
    int* __restrict__ amax_arr,          // [NTOK]
    float* __restrict__ partial)         // [256][16]: 0..7 prob sums, 8..15 counts
{
    const int tid = threadIdx.x;
    const int wave = tid >> 6, lane = tid & 63;
    __shared__ float pr[4][16];

    float wacc[16];
#pragma unroll
    for (int j = 0; j < 16; j++) wacc[j] = 0.0f;

    for (int i = 0; i < 4; i++) {
        const int n = blockIdx.x * 16 + wave * 4 + i;
        const float4* xr = (const float4*)(x + (size_t)n * DDIM);
        float4 xv[4];
#pragma unroll
        for (int j = 0; j < 4; j++) xv[j] = xr[lane + j * 64];

        float acc[NEXP];
#pragma unroll
        for (int e = 0; e < NEXP; e++) acc[e] = 0.0f;
#pragma unroll
        for (int j = 0; j < 4; j++) {
            const int dbase = (lane + j * 64) * 4;
#pragma unroll
            for (int c = 0; c < 4; c++) {
                const float4* wr = (const float4*)(w_switch + (size_t)(dbase + c) * NEXP);
                float4 w0 = wr[0], w1 = wr[1];
                float xvc = ((const float*)&xv[j])[c];
                acc[0] += xvc * w0.x; acc[1] += xvc * w0.y;
                acc[2] += xvc * w0.z; acc[3] += xvc * w0.w;
                acc[4] += xvc * w1.x; acc[5] += xvc * w1.y;
                acc[6] += xvc * w1.z; acc[7] += xvc * w1.w;
            }
        }
#pragma unroll
        for (int e = 0; e < NEXP; e++) {
            float v = acc[e];
#pragma unroll
            for (int off = 32; off > 0; off >>= 1) v += __shfl_xor(v, off, 64);
            acc[e] = v;
        }
        float mx = -1e30f;
#pragma unroll
        for (int e = 0; e < NEXP; e++) {
            acc[e] += b_switch[e];
            mx = fmaxf(mx, acc[e]);
        }
        float sum = 0.0f;
#pragma unroll
        for (int e = 0; e < NEXP; e++) { acc[e] = __expf(acc[e] - mx); sum += acc[e]; }
        float inv = 1.0f / sum;
        float pmax = -1.0f; int amax = 0;
#pragma unroll
        for (int e = 0; e < NEXP; e++) {
            float p = acc[e] * inv;
            acc[e] = p;
            if (p > pmax) { pmax = p; amax = e; }
        }
#pragma unroll
        for (int e = 0; e < NEXP; e++) {
            wacc[e] += acc[e];
            wacc[8 + e] += (amax == e) ? 1.0f : 0.0f;
        }
        if (lane == 0) amax_arr[n] = amax;
#pragma unroll
        for (int j = 0; j < 4; j++) {
            ushort4 pk;
            __hip_bfloat16* pp = (__hip_bfloat16*)&pk;
            pp[0] = __float2bfloat16(xv[j].x * pmax);
            pp[1] = __float2bfloat16(xv[j].y * pmax);
            pp[2] = __float2bfloat16(xv[j].z * pmax);
            pp[3] = __float2bfloat16(xv[j].w * pmax);
            *(ushort4*)(xs + (size_t)n * DDIM + (lane + j * 64) * 4) = pk;
        }
    }
    if (lane == 0) {
#pragma unroll
        for (int j = 0; j < 16; j++) pr[wave][j] = wacc[j];
    }
    __syncthreads();
    if (tid < 16)
        partial[blockIdx.x * 16 + tid] = pr[0][tid] + pr[1][tid] + pr[2][tid] + pr[3][tid];
}

// ---------------- bucket: per-expert token lists, ballot-aggregated, LDS counter ----------
__global__ __launch_bounds__(1024) void bucket_kernel(
    const int* __restrict__ amax_arr, int* __restrict__ bucket, int* __restrict__ ecnt)
{
    const int e = blockIdx.x;
    __shared__ int ctr;
    if (threadIdx.x == 0) ctr = 0;
    __syncthreads();
    const int lane = threadIdx.x & 63;
    for (int c = 0; c < NTOK; c += 1024) {
        int t = c + threadIdx.x;
        bool my = (amax_arr[t] == e);
        unsigned long long mask = __ballot(my);
        int cnt = __popcll(mask);
        int base = 0;
        if (lane == 0 && cnt) base = atomicAdd(&ctr, cnt);
        base = __shfl(base, 0, 64);
        if (my) {
            int rank = __popcll(mask & ((1ull << lane) - 1ull));
            bucket[e * NTOK + base + rank] = t;
        }
    }
    __syncthreads();
    if (threadIdx.x == 0) ecnt[e] = ctr;
}

// ---------------- finalize + m-tile table ----------------
__global__ __launch_bounds__(256) void finalize_table_kernel(
    const float* __restrict__ partial, const int* __restrict__ ecnt,
    float* __restrict__ out_tail, int* __restrict__ table)
{
    __shared__ float red[16][16];
    const int j = threadIdx.x & 15, g = threadIdx.x >> 4;
    float s = 0.0f;
    for (int k = 0; k < 16; k++) s += partial[(size_t)(g + k * 16) * 16 + j];
    red[g][j] = s;
    __syncthreads();
    if (threadIdx.x < 16) {
        float t = 0.0f;
        for (int k = 0; k < 16; k++) t += red[k][threadIdx.x];
        int dst = (threadIdx.x < 8) ? (8 + threadIdx.x) : (threadIdx.x - 8);
        out_tail[dst] = t;
    }
    if (threadIdx.x == 16) out_tail[16] = 0.0f;  // n_dropped
    if (threadIdx.x == 0) {
        int idx = 0;
        for (int e = 0; e < NEXP; e++) {
            int cnt = ecnt[e];
            for (int m0 = 0; m0 < cnt; m0 += 128) table[idx++] = (e << 16) | m0;
        }
        for (; idx < MAXTILES; idx++) table[idx] = -1;
    }
}

// ---------------- transpose+convert: fp32 [E,R,C] -> bf16 [E,C,R] ----------------
template <int R, int C>
__global__ __launch_bounds__(256) void transpose_kernel(
    const float* __restrict__ in, __hip_bfloat16* __restrict__ outp)
{
    const int e = blockIdx.z;
    const int r0 = blockIdx.y * 64, c0 = blockIdx.x * 64;
    __shared__ __hip_bfloat16 t[64 * 65];
    const int tid = threadIdx.x;
    const int ri = tid >> 4, c4 = (tid & 15) * 4;
    const float* src = in + ((size_t)e * R + r0) * C + c0;
#pragma unroll
    for (int rr = 0; rr < 4; rr++) {
        int r = ri + rr * 16;
        float4 v = *(const float4*)(src + (size_t)r * C + c4);
        t[r * 65 + c4 + 0] = __float2bfloat16(v.x);
        t[r * 65 + c4 + 1] = __float2bfloat16(v.y);
        t[r * 65 + c4 + 2] = __float2bfloat16(v.z);
        t[r * 65 + c4 + 3] = __float2bfloat16(v.w);
    }
    __syncthreads();
    const int co = tid >> 2, m = tid & 3;
    u16x8 v0, v1;
#pragma unroll
    for (int idx = 0; idx < 8; idx++)
        ((unsigned short*)&v0)[idx] = *(const unsigned short*)&t[(m * 16 + idx) * 65 + co];
#pragma unroll
    for (int idx = 0; idx < 8; idx++)
        ((unsigned short*)&v1)[idx] = *(const unsigned short*)&t[(m * 16 + idx + 8) * 65 + co];
    __hip_bfloat16* dst = outp + ((size_t)e * C + c0 + co) * R + r0 + m * 16;
    *(u16x8*)(dst) = v0;
    *(u16x8*)(dst + 8) = v1;
}

// ---------------- grouped GEMM body: 128x128 tile, BK=32, R0 structure + XCD-affine remap --
// 1-D grid; decode keeps all n-blocks of one m-tile (same A rows) on ONE XCD (bid&7),
// sweeping x consecutively within the XCD so the A-tile stays L2-resident (T1).
// MODE 0: h = bf16(relu(acc + bias)), KS=1.
// MODE 1: unsafeAtomicAdd fp32 into zeroed out; z==0 block also adds bias.
template <int MODE, int K, int NN, int KS, int NX>
__device__ __forceinline__ void gemm_body(
    const __hip_bfloat16* __restrict__ A,
    const __hip_bfloat16* __restrict__ Bt,
    const float* __restrict__ bias,
    const int* __restrict__ bucket,
    const int* __restrict__ ecnt,
    const int* __restrict__ table,
    void* __restrict__ Out)
{
    // XCD-affine decode: xcd = bid&7 pins m-tile residue; x sweeps fastest within XCD.
    const int bid = blockIdx.x;
    const int xcd = bid & 7;
    const int q = bid >> 3;
    const int x = q % NX;
    const int yk = (q / NX) % (MAXTILES / 8);
    const int z = q / (NX * (MAXTILES / 8));
    const int y = xcd + 8 * yk;

    const int entry = table[y];
    if (entry < 0) return;
    const int e = entry >> 16;
    const int m0 = entry & 0xffff;
    const int cnt = ecnt[e];
    const int n0 = x * 128;
    const int kbase = (K / KS) * z;

    __shared__ __align__(16) __hip_bfloat16 Asm[128 * 32];
    __shared__ __align__(16) __hip_bfloat16 Bsm[128 * 32];
    __shared__ int toks[128];

    const int tid = threadIdx.x;
    if (tid < 128) {
        int r = m0 + tid;
        toks[tid] = bucket[e * NTOK + (r < cnt ? r : cnt - 1)];
    }
    __syncthreads();

    const int wave = tid >> 6, lane = tid & 63;
    const int r = lane & 15, kq = lane >> 4;
    const int g0 = 2 * wave, g1 = 2 * wave + 1;

    const __hip_bfloat16* pA0 = A + (size_t)toks[g0 * 16 + r] * K + kbase + kq * 8;
    const __hip_bfloat16* pA1 = A + (size_t)toks[g1 * 16 + r] * K + kbase + kq * 8;
    const __hip_bfloat16* pB0 = Bt + ((size_t)e * NN + n0 + g0 * 16 + r) * K + kbase + kq * 8;
    const __hip_bfloat16* pB1 = Bt + ((size_t)e * NN + n0 + g1 * 16 + r) * K + kbase + kq * 8;
    char* lA0 = (char*)Asm + g0 * 1024;
    char* lA1 = (char*)Asm + g1 * 1024;
    char* lB0 = (char*)Bsm + g0 * 1024;
    char* lB1 = (char*)Bsm + g1 * 1024;

    const int wm = wave & 1, wn = wave >> 1;
    f32x4 acc[4][4];
#pragma unroll
    for (int t = 0; t < 4; t++)
#pragma unroll
        for (int u = 0; u < 4; u++) acc[t][u] = (f32x4){0.f, 0.f, 0.f, 0.f};

    for (int k0 = 0; k0 < K / KS; k0 += 32) {
        GLDS(pA0, lA0); GLDS(pA1, lA1);
        GLDS(pB0, lB0); GLDS(pB1, lB1);
        pA0 += 32; pA1 += 32; pB0 += 32; pB1 += 32;
        __syncthreads();
        bf16x8 a[4], b[4];
#pragma unroll
        for (int t = 0; t < 4; t++)
            a[t] = *(const bf16x8*)((const char*)Asm + (wm * 4 + t) * 1024 + lane * 16);
#pragma unroll
        for (int u = 0; u < 4; u++)
            b[u] = *(const bf16x8*)((const char*)Bsm + (wn * 4 + u) * 1024 + lane * 16);
#pragma unroll
        for (int t = 0; t < 4; t++)
#pragma unroll
            for (int u = 0; u < 4; u++)
                acc[t][u] = __builtin_amdgcn_mfma_f32_16x16x32_bf16(a[t], b[u], acc[t][u], 0, 0, 0);
        __syncthreads();
    }

    const int quad = lane >> 4, l15 = lane & 15;
    float bv[4];
#pragma unroll
    for (int u = 0; u < 4; u++) {
        if (MODE == 0)
            bv[u] = bias[(size_t)e * NN + n0 + wn * 64 + u * 16 + l15];
        else
            bv[u] = (z == 0) ? bias[(size_t)e * NN + n0 + wn * 64 + u * 16 + l15] : 0.0f;
    }
#pragma unroll
    for (int t = 0; t < 4; t++) {
#pragma unroll
        for (int rr = 0; rr < 4; rr++) {
            int row = wm * 64 + t * 16 + quad * 4 + rr;
            if (m0 + row < cnt) {
                int tok = toks[row];
#pragma unroll
                for (int u = 0; u < 4; u++) {
                    int col = n0 + wn * 64 + u * 16 + l15;
                    float v = acc[t][u][rr] + bv[u];
                    if (MODE == 0) {
                        v = fmaxf(v, 0.0f);
                        ((__hip_bfloat16*)Out)[(size_t)tok * NN + col] = __float2bfloat16(v);
                    } else {
                        unsafeAtomicAdd(&((float*)Out)[(size_t)tok * NN + col], v);
                    }
                }
            }
        }
    }
}

__global__ __launch_bounds__(256) void gemm_ffn1(
    const __hip_bfloat16* __restrict__ A, const __hip_bfloat16* __restrict__ Bt,
    const float* __restrict__ bias, const int* __restrict__ bucket,
    const int* __restrict__ ecnt, const int* __restrict__ table, void* __restrict__ Out)
{
    gemm_body<0, DDIM, FDIM, 1, FDIM / 128>(A, Bt, bias, bucket, ecnt, table, Out);
}

__global__ __launch_bounds__(256) void gemm_ffn2(
    const __hip_bfloat16* __restrict__ A, const __hip_bfloat16* __restrict__ Bt,
    const float* __restrict__ bias, const int* __restrict__ bucket,
    const int* __restrict__ ecnt, const int* __restrict__ table, void* __restrict__ Out)
{
    gemm_body<1, FDIM, DDIM, 2, DDIM / 128>(A, Bt, bias, bucket, ecnt, table, Out);
}

extern "C" void kernel_launch(void* const* d_in, const int* in_sizes, int n_in,
                              void* d_out, int out_size, void* d_ws, size_t ws_size,
                              hipStream_t stream) {
    const float* x        = (const float*)d_in[0];
    const float* w_switch = (const float*)d_in[1];
    const float* b_switch = (const float*)d_in[2];
    const float* w1       = (const float*)d_in[3];
    const float* b1       = (const float*)d_in[4];
    const float* w2       = (const float*)d_in[5];
    const float* b2       = (const float*)d_in[6];

    float* out = (float*)d_out;
    float* out_tail = out + (size_t)NTOK * DDIM;

    char* ws = (char*)d_ws;
    __hip_bfloat16* xs = (__hip_bfloat16*)(ws);                        // 8 MB
    __hip_bfloat16* h  = (__hip_bfloat16*)(ws + 8388608ull);           // 32 MB
    __hip_bfloat16* wt = (__hip_bfloat16*)(ws + 41943040ull);          // 64 MB (shared w1t/w2t)
    int* bucket        = (int*)(ws + 109051904ull);                    // 128 KB
    int* amax_arr      = (int*)(ws + 109182976ull);                    // 16 KB
    float* partial     = (float*)(ws + 109199360ull);                  // 16 KB
    int* ecnt          = (int*)(ws + 109215744ull);                    // 32 B
    int* table         = (int*)(ws + 109215776ull);                    // 160 B

    // zero the accumulation target (replaces init_out; b2 bias folded into z==0 GEMM blocks)
    hipMemsetAsync(out, 0, (size_t)NTOK * DDIM * sizeof(float), stream);

    hipLaunchKernelGGL(route_kernel, dim3(256), dim3(256), 0, stream,
                       x, w_switch, b_switch, xs, amax_arr, partial);
    hipLaunchKernelGGL(bucket_kernel, dim3(NEXP), dim3(1024), 0, stream,
                       amax_arr, bucket, ecnt);
    hipLaunchKernelGGL(finalize_table_kernel, dim3(1), dim3(256), 0, stream,
                       partial, ecnt, out_tail, table);

    // w1 [E,1024,4096] -> w1t [E,4096,1024]
    hipLaunchKernelGGL((transpose_kernel<DDIM, FDIM>), dim3(FDIM / 64, DDIM / 64, NEXP),
                       dim3(256), 0, stream, w1, wt);
    hipLaunchKernelGGL(gemm_ffn1, dim3((FDIM / 128) * MAXTILES), dim3(256), 0, stream,
                       xs, wt, b1, bucket, ecnt, table, (void*)h);

    // w2 [E,4096,1024] -> w2t [E,1024,4096]  (reuses wt after gemm1)
    hipLaunchKernelGGL((transpose_kernel<FDIM, DDIM>), dim3(DDIM / 64, FDIM / 64, NEXP),
                       dim3(256), 0, stream, w2, wt);
    hipLaunchKernelGGL(gemm_ffn2, dim3((DDIM / 128) * MAXTILES * 2), dim3(256), 0, stream,
                       h, wt, b2, bucket, ecnt, table, (void*)out);
}

// Round 4
// 512.989 us; speedup vs baseline: 1.0840x; 1.0044x over previous
//
#include <hip/hip_runtime.h>
#include <hip/hip_bf16.h>

#define NTOK 4096
#define DDIM 1024
#define NEXP 8
#define FDIM 4096
#define MAXTILES 40

typedef __attribute__((ext_vector_type(4))) float f32x4;
typedef __attribute__((ext_vector_type(8))) short bf16x8;
typedef __attribute__((ext_vector_type(8))) unsigned short u16x8;

#define GLDS(g, l) __builtin_amdgcn_global_load_lds( \
    (const __attribute__((address_space(1))) unsigned int*)(g), \
    (__attribute__((address_space(3))) unsigned int*)(l), 16, 0, 0)

// 32-bit LDS byte offset for inline-asm ds_read (addrspace(3) pointers are 32-bit offsets)
#define LDSOFF(p) ((unsigned)(unsigned long long)(__attribute__((address_space(3))) char*)(p))

// inline-asm ds_read_b128: invisible to compiler alias analysis, so NO auto vmcnt(0)
// is inserted between global_load_lds staging and these reads (the R1/R2 failure mode).
#define DSR(dst, a, o) asm volatile("ds_read_b128 %0, %1 offset:" o : "=v"(dst) : "v"(a))

// ---------------- route: no global atomics. Writes xs (bf16), amax[], partial[256][16] ----
__global__ __launch_bounds__(256) void route_kernel(
    const float* __restrict__ x,         // [NTOK, D]
    const float* __restrict__ w_switch,  // [D, E]
    const float* __restrict__ b_switch,  // [E]
    __hip_bfloat16* __restrict__ xs,     // [NTOK, D]
    int* __restrict__ amax_arr,          // [NTOK]
    float* __restrict__ partial)         // [256][16]: 0..7 prob sums, 8..15 counts
{
    const int tid = threadIdx.x;
    const int wave = tid >> 6, lane = tid & 63;
    __shared__ float pr[4][16];

    float wacc[16];
#pragma unroll
    for (int j = 0; j < 16; j++) wacc[j] = 0.0f;

    for (int i = 0; i < 4; i++) {
        const int n = blockIdx.x * 16 + wave * 4 + i;
        const float4* xr = (const float4*)(x + (size_t)n * DDIM);
        float4 xv[4];
#pragma unroll
        for (int j = 0; j < 4; j++) xv[j] = xr[lane + j * 64];

        float acc[NEXP];
#pragma unroll
        for (int e = 0; e < NEXP; e++) acc[e] = 0.0f;
#pragma unroll
        for (int j = 0; j < 4; j++) {
            const int dbase = (lane + j * 64) * 4;
#pragma unroll
            for (int c = 0; c < 4; c++) {
                const float4* wr = (const float4*)(w_switch + (size_t)(dbase + c) * NEXP);
                float4 w0 = wr[0], w1 = wr[1];
                float xvc = ((const float*)&xv[j])[c];
                acc[0] += xvc * w0.x; acc[1] += xvc * w0.y;
                acc[2] += xvc * w0.z; acc[3] += xvc * w0.w;
                acc[4] += xvc * w1.x; acc[5] += xvc * w1.y;
                acc[6] += xvc * w1.z; acc[7] += xvc * w1.w;
            }
        }
#pragma unroll
        for (int e = 0; e < NEXP; e++) {
            float v = acc[e];
#pragma unroll
            for (int off = 32; off > 0; off >>= 1) v += __shfl_xor(v, off, 64);
            acc[e] = v;
        }
        float mx = -1e30f;
#pragma unroll
        for (int e = 0; e < NEXP; e++) {
            acc[e] += b_switch[e];
            mx = fmaxf(mx, acc[e]);
        }
        float sum = 0.0f;
#pragma unroll
        for (int e = 0; e < NEXP; e++) { acc[e] = __expf(acc[e] - mx); sum += acc[e]; }
        float inv = 1.0f / sum;
        float pmax = -1.0f; int amax = 0;
#pragma unroll
        for (int e = 0; e < NEXP; e++) {
            float p = acc[e] * inv;
            acc[e] = p;
            if (p > pmax) { pmax = p; amax = e; }
        }
#pragma unroll
        for (int e = 0; e < NEXP; e++) {
            wacc[e] += acc[e];
            wacc[8 + e] += (amax == e) ? 1.0f : 0.0f;
        }
        if (lane == 0) amax_arr[n] = amax;
#pragma unroll
        for (int j = 0; j < 4; j++) {
            ushort4 pk;
            __hip_bfloat16* pp = (__hip_bfloat16*)&pk;
            pp[0] = __float2bfloat16(xv[j].x * pmax);
            pp[1] = __float2bfloat16(xv[j].y * pmax);
            pp[2] = __float2bfloat16(xv[j].z * pmax);
            pp[3] = __float2bfloat16(xv[j].w * pmax);
            *(ushort4*)(xs + (size_t)n * DDIM + (lane + j * 64) * 4) = pk;
        }
    }
    if (lane == 0) {
#pragma unroll
        for (int j = 0; j < 16; j++) pr[wave][j] = wacc[j];
    }
    __syncthreads();
    if (tid < 16)
        partial[blockIdx.x * 16 + tid] = pr[0][tid] + pr[1][tid] + pr[2][tid] + pr[3][tid];
}

// ---------------- bucket: per-expert token lists, ballot-aggregated, LDS counter ----------
__global__ __launch_bounds__(1024) void bucket_kernel(
    const int* __restrict__ amax_arr, int* __restrict__ bucket, int* __restrict__ ecnt)
{
    const int e = blockIdx.x;
    __shared__ int ctr;
    if (threadIdx.x == 0) ctr = 0;
    __syncthreads();
    const int lane = threadIdx.x & 63;
    for (int c = 0; c < NTOK; c += 1024) {
        int t = c + threadIdx.x;
        bool my = (amax_arr[t] == e);
        unsigned long long mask = __ballot(my);
        int cnt = __popcll(mask);
        int base = 0;
        if (lane == 0 && cnt) base = atomicAdd(&ctr, cnt);
        base = __shfl(base, 0, 64);
        if (my) {
            int rank = __popcll(mask & ((1ull << lane) - 1ull));
            bucket[e * NTOK + base + rank] = t;
        }
    }
    __syncthreads();
    if (threadIdx.x == 0) ecnt[e] = ctr;
}

// ---------------- finalize + m-tile table ----------------
__global__ __launch_bounds__(256) void finalize_table_kernel(
    const float* __restrict__ partial, const int* __restrict__ ecnt,
    float* __restrict__ out_tail, int* __restrict__ table)
{
    __shared__ float red[16][16];
    const int j = threadIdx.x & 15, g = threadIdx.x >> 4;
    float s = 0.0f;
    for (int k = 0; k < 16; k++) s += partial[(size_t)(g + k * 16) * 16 + j];
    red[g][j] = s;
    __syncthreads();
    if (threadIdx.x < 16) {
        float t = 0.0f;
        for (int k = 0; k < 16; k++) t += red[k][threadIdx.x];
        int dst = (threadIdx.x < 8) ? (8 + threadIdx.x) : (threadIdx.x - 8);
        out_tail[dst] = t;
    }
    if (threadIdx.x == 16) out_tail[16] = 0.0f;  // n_dropped
    if (threadIdx.x == 0) {
        int idx = 0;
        for (int e = 0; e < NEXP; e++) {
            int cnt = ecnt[e];
            for (int m0 = 0; m0 < cnt; m0 += 128) table[idx++] = (e << 16) | m0;
        }
        for (; idx < MAXTILES; idx++) table[idx] = -1;
    }
}

// ---------------- transpose+convert: fp32 [E,R,C] -> bf16 [E,C,R] ----------------
template <int R, int C>
__global__ __launch_bounds__(256) void transpose_kernel(
    const float* __restrict__ in, __hip_bfloat16* __restrict__ outp)
{
    const int e = blockIdx.z;
    const int r0 = blockIdx.y * 64, c0 = blockIdx.x * 64;
    __shared__ __hip_bfloat16 t[64 * 65];
    const int tid = threadIdx.x;
    const int ri = tid >> 4, c4 = (tid & 15) * 4;
    const float* src = in + ((size_t)e * R + r0) * C + c0;
#pragma unroll
    for (int rr = 0; rr < 4; rr++) {
        int r = ri + rr * 16;
        float4 v = *(const float4*)(src + (size_t)r * C + c4);
        t[r * 65 + c4 + 0] = __float2bfloat16(v.x);
        t[r * 65 + c4 + 1] = __float2bfloat16(v.y);
        t[r * 65 + c4 + 2] = __float2bfloat16(v.z);
        t[r * 65 + c4 + 3] = __float2bfloat16(v.w);
    }
    __syncthreads();
    const int co = tid >> 2, m = tid & 3;
    u16x8 v0, v1;
#pragma unroll
    for (int idx = 0; idx < 8; idx++)
        ((unsigned short*)&v0)[idx] = *(const unsigned short*)&t[(m * 16 + idx) * 65 + co];
#pragma unroll
    for (int idx = 0; idx < 8; idx++)
        ((unsigned short*)&v1)[idx] = *(const unsigned short*)&t[(m * 16 + idx + 8) * 65 + co];
    __hip_bfloat16* dst = outp + ((size_t)e * C + c0 + co) * R + r0 + m * 16;
    *(u16x8*)(dst) = v0;
    *(u16x8*)(dst + 8) = v1;
}

// ---------------- grouped GEMM body: 128x128, BK=32, depth-2 counted-vmcnt (T3+T4) -------
// 3 LDS buffers. Iter t: stage tile t+2 (GLDS), asm ds_read tile t, lgkmcnt(0)+sched_barrier,
// 16 MFMA, then vmcnt(4) (tile t+1 landed; t+2 stays in flight) + raw s_barrier.
// ds_reads are inline asm so the compiler cannot insert its own vmcnt(0) drain (the R1 bug).
// XCD-affine decode (T1): xcd = bid&7 pins the m-tile; x sweeps fastest within the XCD.
// MODE 0: h = bf16(relu(acc + bias)), KS=1.
// MODE 1: unsafeAtomicAdd fp32 into zeroed out; z==0 block also adds bias.
template <int MODE, int K, int NN, int KS, int NX>
__device__ __forceinline__ void gemm_body(
    const __hip_bfloat16* __restrict__ A,
    const __hip_bfloat16* __restrict__ Bt,
    const float* __restrict__ bias,
    const int* __restrict__ bucket,
    const int* __restrict__ ecnt,
    const int* __restrict__ table,
    void* __restrict__ Out)
{
    const int bid = blockIdx.x;
    const int xcd = bid & 7;
    const int q = bid >> 3;
    const int x = q % NX;
    const int yk = (q / NX) % (MAXTILES / 8);
    const int z = q / (NX * (MAXTILES / 8));
    const int y = xcd + 8 * yk;

    const int entry = table[y];
    if (entry < 0) return;
    const int e = entry >> 16;
    const int m0 = entry & 0xffff;
    const int cnt = ecnt[e];
    const int n0 = x * 128;
    const int kbase = (K / KS) * z;

    __shared__ __align__(16) __hip_bfloat16 Asm[3][128 * 32];  // 3 x 8 KB
    __shared__ __align__(16) __hip_bfloat16 Bsm[3][128 * 32];  // 3 x 8 KB
    __shared__ int toks[128];

    const int tid = threadIdx.x;
    if (tid < 128) {
        int r = m0 + tid;
        toks[tid] = bucket[e * NTOK + (r < cnt ? r : cnt - 1)];
    }
    __syncthreads();

    const int wave = tid >> 6, lane = tid & 63;
    const int r = lane & 15, kq = lane >> 4;
    const int g0 = 2 * wave;

    const __hip_bfloat16* pA0 = A + (size_t)toks[g0 * 16 + r] * K + kbase + kq * 8;
    const __hip_bfloat16* pA1 = A + (size_t)toks[(g0 + 1) * 16 + r] * K + kbase + kq * 8;
    const __hip_bfloat16* pB0 = Bt + ((size_t)e * NN + n0 + g0 * 16 + r) * K + kbase + kq * 8;
    const __hip_bfloat16* pB1 = Bt + ((size_t)e * NN + n0 + (g0 + 1) * 16 + r) * K + kbase + kq * 8;

    const int wm = wave & 1, wn = wave >> 1;
    // wave-invariant asm ds_read addresses (buffer 0); offset imm walks the 4 sub-chunks
    const unsigned aBase = LDSOFF((char*)Asm) + wm * 4096 + lane * 16;
    const unsigned bBase = LDSOFF((char*)Bsm) + wn * 4096 + lane * 16;

    f32x4 acc[4][4];
#pragma unroll
    for (int t = 0; t < 4; t++)
#pragma unroll
        for (int u = 0; u < 4; u++) acc[t][u] = (f32x4){0.f, 0.f, 0.f, 0.f};

    constexpr int NSTEP = (K / KS) / 32;
    static_assert(NSTEP >= 3, "pipeline needs >=3 K-steps");

    auto stage = [&](int b) {
        char* la = (char*)Asm + b * 8192 + g0 * 1024;
        char* lb = (char*)Bsm + b * 8192 + g0 * 1024;
        GLDS(pA0, la); GLDS(pA1, la + 1024);
        GLDS(pB0, lb); GLDS(pB1, lb + 1024);
        pA0 += 32; pA1 += 32; pB0 += 32; pB1 += 32;
    };

    // prologue: tiles 0,1 in flight; wait only for tile 0 (oldest 4 of 8)
    stage(0);
    stage(1);
    asm volatile("s_waitcnt vmcnt(4)");
    __builtin_amdgcn_s_barrier();

    int cb = 0, sb = 2;  // compute-buffer, stage-buffer indices (mod 3)
    for (int t = 0; t < NSTEP; ++t) {
        if (t + 2 < NSTEP) stage(sb);

        const unsigned aA = aBase + cb * 8192;
        const unsigned aB = bBase + cb * 8192;
        bf16x8 af[4], bf_[4];
        DSR(af[0], aA, "0");    DSR(af[1], aA, "1024");
        DSR(af[2], aA, "2048"); DSR(af[3], aA, "3072");
        DSR(bf_[0], aB, "0");    DSR(bf_[1], aB, "1024");
        DSR(bf_[2], aB, "2048"); DSR(bf_[3], aB, "3072");
        asm volatile("s_waitcnt lgkmcnt(0)");
        __builtin_amdgcn_sched_barrier(0);   // keep MFMA below the lgkmcnt (rule #18)

#pragma unroll
        for (int t4 = 0; t4 < 4; t4++)
#pragma unroll
            for (int u = 0; u < 4; u++)
                acc[t4][u] = __builtin_amdgcn_mfma_f32_16x16x32_bf16(af[t4], bf_[u], acc[t4][u], 0, 0, 0);

        if (t + 2 < NSTEP) {
            asm volatile("s_waitcnt vmcnt(4)");  // tile t+1 landed; t+2 stays in flight
            __builtin_amdgcn_s_barrier();
        } else if (t + 1 < NSTEP) {
            asm volatile("s_waitcnt vmcnt(0)");  // epilogue: only tile t+1 outstanding
            __builtin_amdgcn_s_barrier();
        }
        cb = (cb == 2) ? 0 : cb + 1;
        sb = (sb == 2) ? 0 : sb + 1;
    }

    const int quad = lane >> 4, l15 = lane & 15;
    float bv[4];
#pragma unroll
    for (int u = 0; u < 4; u++) {
        if (MODE == 0)
            bv[u] = bias[(size_t)e * NN + n0 + wn * 64 + u * 16 + l15];
        else
            bv[u] = (z == 0) ? bias[(size_t)e * NN + n0 + wn * 64 + u * 16 + l15] : 0.0f;
    }
#pragma unroll
    for (int t = 0; t < 4; t++) {
#pragma unroll
        for (int rr = 0; rr < 4; rr++) {
            int row = wm * 64 + t * 16 + quad * 4 + rr;
            if (m0 + row < cnt) {
                int tok = toks[row];
#pragma unroll
                for (int u = 0; u < 4; u++) {
                    int col = n0 + wn * 64 + u * 16 + l15;
                    float v = acc[t][u][rr] + bv[u];
                    if (MODE == 0) {
                        v = fmaxf(v, 0.0f);
                        ((__hip_bfloat16*)Out)[(size_t)tok * NN + col] = __float2bfloat16(v);
                    } else {
                        unsafeAtomicAdd(&((float*)Out)[(size_t)tok * NN + col], v);
                    }
                }
            }
        }
    }
}

__global__ __launch_bounds__(256) void gemm_ffn1(
    const __hip_bfloat16* __restrict__ A, const __hip_bfloat16* __restrict__ Bt,
    const float* __restrict__ bias, const int* __restrict__ bucket,
    const int* __restrict__ ecnt, const int* __restrict__ table, void* __restrict__ Out)
{
    gemm_body<0, DDIM, FDIM, 1, FDIM / 128>(A, Bt, bias, bucket, ecnt, table, Out);
}

__global__ __launch_bounds__(256) void gemm_ffn2(
    const __hip_bfloat16* __restrict__ A, const __hip_bfloat16* __restrict__ Bt,
    const float* __restrict__ bias, const int* __restrict__ bucket,
    const int* __restrict__ ecnt, const int* __restrict__ table, void* __restrict__ Out)
{
    gemm_body<1, FDIM, DDIM, 2, DDIM / 128>(A, Bt, bias, bucket, ecnt, table, Out);
}

extern "C" void kernel_launch(void* const* d_in, const int* in_sizes, int n_in,
                              void* d_out, int out_size, void* d_ws, size_t ws_size,
                              hipStream_t stream) {
    const float* x        = (const float*)d_in[0];
    const float* w_switch = (const float*)d_in[1];
    const float* b_switch = (const float*)d_in[2];
    const float* w1       = (const float*)d_in[3];
    const float* b1       = (const float*)d_in[4];
    const float* w2       = (const float*)d_in[5];
    const float* b2       = (const float*)d_in[6];

    float* out = (float*)d_out;
    float* out_tail = out + (size_t)NTOK * DDIM;

    char* ws = (char*)d_ws;
    __hip_bfloat16* xs = (__hip_bfloat16*)(ws);                        // 8 MB
    __hip_bfloat16* h  = (__hip_bfloat16*)(ws + 8388608ull);           // 32 MB
    __hip_bfloat16* wt = (__hip_bfloat16*)(ws + 41943040ull);          // 64 MB (shared w1t/w2t)
    int* bucket        = (int*)(ws + 109051904ull);                    // 128 KB
    int* amax_arr      = (int*)(ws + 109182976ull);                    // 16 KB
    float* partial     = (float*)(ws + 109199360ull);                  // 16 KB
    int* ecnt          = (int*)(ws + 109215744ull);                    // 32 B
    int* table         = (int*)(ws + 109215776ull);                    // 160 B

    // zero the accumulation target (replaces init_out; b2 bias folded into z==0 GEMM blocks)
    hipMemsetAsync(out, 0, (size_t)NTOK * DDIM * sizeof(float), stream);

    hipLaunchKernelGGL(route_kernel, dim3(256), dim3(256), 0, stream,
                       x, w_switch, b_switch, xs, amax_arr, partial);
    hipLaunchKernelGGL(bucket_kernel, dim3(NEXP), dim3(1024), 0, stream,
                       amax_arr, bucket, ecnt);
    hipLaunchKernelGGL(finalize_table_kernel, dim3(1), dim3(256), 0, stream,
                       partial, ecnt, out_tail, table);

    // w1 [E,1024,4096] -> w1t [E,4096,1024]
    hipLaunchKernelGGL((transpose_kernel<DDIM, FDIM>), dim3(FDIM / 64, DDIM / 64, NEXP),
                       dim3(256), 0, stream, w1, wt);
    hipLaunchKernelGGL(gemm_ffn1, dim3((FDIM / 128) * MAXTILES), dim3(256), 0, stream,
                       xs, wt, b1, bucket, ecnt, table, (void*)h);

    // w2 [E,4096,1024] -> w2t [E,1024,4096]  (reuses wt after gemm1)
    hipLaunchKernelGGL((transpose_kernel<FDIM, DDIM>), dim3(DDIM / 64, FDIM / 64, NEXP),
                       dim3(256), 0, stream, w2, wt);
    hipLaunchKernelGGL(gemm_ffn2, dim3((DDIM / 128) * MAXTILES * 2), dim3(256), 0, stream,
                       h, wt, b2, bucket, ecnt, table, (void*)out);
}

// Round 5
// 485.323 us; speedup vs baseline: 1.1457x; 1.0570x over previous
//
#include <hip/hip_runtime.h>
#include <hip/hip_bf16.h>

#define NTOK 4096
#define DDIM 1024
#define NEXP 8
#define FDIM 4096
#define MAXTILES 40

typedef __attribute__((ext_vector_type(4))) float f32x4;
typedef __attribute__((ext_vector_type(8))) short bf16x8;
typedef __attribute__((ext_vector_type(8))) unsigned short u16x8;

#define GLDS(g, l) __builtin_amdgcn_global_load_lds( \
    (const __attribute__((address_space(1))) unsigned int*)(g), \
    (__attribute__((address_space(3))) unsigned int*)(l), 16, 0, 0)

// ---------------- route: no global atomics. Writes xs (bf16), amax[], partial[256][16] ----
__global__ __launch_bounds__(256) void route_kernel(
    const float* __restrict__ x,         // [NTOK, D]
    const float* __restrict__ w_switch,  // [D, E]
    const float* __restrict__ b_switch,  // [E]
    __hip_bfloat16* __restrict__ xs,     // [NTOK, D]
    int* __restrict__ amax_arr,          // [NTOK]
    float* __restrict__ partial)         // [256][16]: 0..7 prob sums, 8..15 counts
{
    const int tid = threadIdx.x;
    const int wave = tid >> 6, lane = tid & 63;
    __shared__ float pr[4][16];

    float wacc[16];
#pragma unroll
    for (int j = 0; j < 16; j++) wacc[j] = 0.0f;

    for (int i = 0; i < 4; i++) {
        const int n = blockIdx.x * 16 + wave * 4 + i;
        const float4* xr = (const float4*)(x + (size_t)n * DDIM);
        float4 xv[4];
#pragma unroll
        for (int j = 0; j < 4; j++) xv[j] = xr[lane + j * 64];

        float acc[NEXP];
#pragma unroll
        for (int e = 0; e < NEXP; e++) acc[e] = 0.0f;
#pragma unroll
        for (int j = 0; j < 4; j++) {
            const int dbase = (lane + j * 64) * 4;
#pragma unroll
            for (int c = 0; c < 4; c++) {
                const float4* wr = (const float4*)(w_switch + (size_t)(dbase + c) * NEXP);
                float4 w0 = wr[0], w1 = wr[1];
                float xvc = ((const float*)&xv[j])[c];
                acc[0] += xvc * w0.x; acc[1] += xvc * w0.y;
                acc[2] += xvc * w0.z; acc[3] += xvc * w0.w;
                acc[4] += xvc * w1.x; acc[5] += xvc * w1.y;
                acc[6] += xvc * w1.z; acc[7] += xvc * w1.w;
            }
        }
#pragma unroll
        for (int e = 0; e < NEXP; e++) {
            float v = acc[e];
#pragma unroll
            for (int off = 32; off > 0; off >>= 1) v += __shfl_xor(v, off, 64);
            acc[e] = v;
        }
        float mx = -1e30f;
#pragma unroll
        for (int e = 0; e < NEXP; e++) {
            acc[e] += b_switch[e];
            mx = fmaxf(mx, acc[e]);
        }
        float sum = 0.0f;
#pragma unroll
        for (int e = 0; e < NEXP; e++) { acc[e] = __expf(acc[e] - mx); sum += acc[e]; }
        float inv = 1.0f / sum;
        float pmax = -1.0f; int amax = 0;
#pragma unroll
        for (int e = 0; e < NEXP; e++) {
            float p = acc[e] * inv;
            acc[e] = p;
            if (p > pmax) { pmax = p; amax = e; }
        }
#pragma unroll
        for (int e = 0; e < NEXP; e++) {
            wacc[e] += acc[e];
            wacc[8 + e] += (amax == e) ? 1.0f : 0.0f;
        }
        if (lane == 0) amax_arr[n] = amax;
#pragma unroll
        for (int j = 0; j < 4; j++) {
            ushort4 pk;
            __hip_bfloat16* pp = (__hip_bfloat16*)&pk;
            pp[0] = __float2bfloat16(xv[j].x * pmax);
            pp[1] = __float2bfloat16(xv[j].y * pmax);
            pp[2] = __float2bfloat16(xv[j].z * pmax);
            pp[3] = __float2bfloat16(xv[j].w * pmax);
            *(ushort4*)(xs + (size_t)n * DDIM + (lane + j * 64) * 4) = pk;
        }
    }
    if (lane == 0) {
#pragma unroll
        for (int j = 0; j < 16; j++) pr[wave][j] = wacc[j];
    }
    __syncthreads();
    if (tid < 16)
        partial[blockIdx.x * 16 + tid] = pr[0][tid] + pr[1][tid] + pr[2][tid] + pr[3][tid];
}

// ---------------- bucket: per-expert token lists, ballot-aggregated, LDS counter ----------
__global__ __launch_bounds__(1024) void bucket_kernel(
    const int* __restrict__ amax_arr, int* __restrict__ bucket, int* __restrict__ ecnt)
{
    const int e = blockIdx.x;
    __shared__ int ctr;
    if (threadIdx.x == 0) ctr = 0;
    __syncthreads();
    const int lane = threadIdx.x & 63;
    for (int c = 0; c < NTOK; c += 1024) {
        int t = c + threadIdx.x;
        bool my = (amax_arr[t] == e);
        unsigned long long mask = __ballot(my);
        int cnt = __popcll(mask);
        int base = 0;
        if (lane == 0 && cnt) base = atomicAdd(&ctr, cnt);
        base = __shfl(base, 0, 64);
        if (my) {
            int rank = __popcll(mask & ((1ull << lane) - 1ull));
            bucket[e * NTOK + base + rank] = t;
        }
    }
    __syncthreads();
    if (threadIdx.x == 0) ecnt[e] = ctr;
}

// ---------------- finalize + m-tile table ----------------
__global__ __launch_bounds__(256) void finalize_table_kernel(
    const float* __restrict__ partial, const int* __restrict__ ecnt,
    float* __restrict__ out_tail, int* __restrict__ table)
{
    __shared__ float red[16][16];
    const int j = threadIdx.x & 15, g = threadIdx.x >> 4;
    float s = 0.0f;
    for (int k = 0; k < 16; k++) s += partial[(size_t)(g + k * 16) * 16 + j];
    red[g][j] = s;
    __syncthreads();
    if (threadIdx.x < 16) {
        float t = 0.0f;
        for (int k = 0; k < 16; k++) t += red[k][threadIdx.x];
        int dst = (threadIdx.x < 8) ? (8 + threadIdx.x) : (threadIdx.x - 8);
        out_tail[dst] = t;
    }
    if (threadIdx.x == 16) out_tail[16] = 0.0f;  // n_dropped
    if (threadIdx.x == 0) {
        int idx = 0;
        for (int e = 0; e < NEXP; e++) {
            int cnt = ecnt[e];
            for (int m0 = 0; m0 < cnt; m0 += 128) table[idx++] = (e << 16) | m0;
        }
        for (; idx < MAXTILES; idx++) table[idx] = -1;
    }
}

// ---------------- transpose+convert: fp32 [E,R,C] -> bf16 [E,C,R] ----------------
template <int R, int C>
__global__ __launch_bounds__(256) void transpose_kernel(
    const float* __restrict__ in, __hip_bfloat16* __restrict__ outp)
{
    const int e = blockIdx.z;
    const int r0 = blockIdx.y * 64, c0 = blockIdx.x * 64;
    __shared__ __hip_bfloat16 t[64 * 65];
    const int tid = threadIdx.x;
    const int ri = tid >> 4, c4 = (tid & 15) * 4;
    const float* src = in + ((size_t)e * R + r0) * C + c0;
#pragma unroll
    for (int rr = 0; rr < 4; rr++) {
        int r = ri + rr * 16;
        float4 v = *(const float4*)(src + (size_t)r * C + c4);
        t[r * 65 + c4 + 0] = __float2bfloat16(v.x);
        t[r * 65 + c4 + 1] = __float2bfloat16(v.y);
        t[r * 65 + c4 + 2] = __float2bfloat16(v.z);
        t[r * 65 + c4 + 3] = __float2bfloat16(v.w);
    }
    __syncthreads();
    const int co = tid >> 2, m = tid & 3;
    u16x8 v0, v1;
#pragma unroll
    for (int idx = 0; idx < 8; idx++)
        ((unsigned short*)&v0)[idx] = *(const unsigned short*)&t[(m * 16 + idx) * 65 + co];
#pragma unroll
    for (int idx = 0; idx < 8; idx++)
        ((unsigned short*)&v1)[idx] = *(const unsigned short*)&t[(m * 16 + idx + 8) * 65 + co];
    __hip_bfloat16* dst = outp + ((size_t)e * C + c0 + co) * R + r0 + m * 16;
    *(u16x8*)(dst) = v0;
    *(u16x8*)(dst + 8) = v1;
}

// ---------------- grouped GEMM body: 128x128 tile, BK=64, single-buffer, 4 blocks/CU -----
// Occupancy-first redesign: 33 KB LDS -> 4 blocks/CU; grid ~4.5 blocks/CU (KS=4 for ffn2).
// BK=64 staging: each GLDS covers 8 rows x 128 B  => half the 64B segments per staged byte
// vs BK=32 (16 rows x 64 B), and half the barrier drains per K.
// XCD-affine decode (T1): xcd = bid&7 pins the m-tile; x sweeps fastest within the XCD.
// MODE 0: h = bf16(relu(acc + bias)), KS=1.
// MODE 1: unsafeAtomicAdd fp32 into zeroed out; z==0 block also adds bias.
template <int MODE, int K, int NN, int KS, int NX>
__device__ __forceinline__ void gemm_body(
    const __hip_bfloat16* __restrict__ A,
    const __hip_bfloat16* __restrict__ Bt,
    const float* __restrict__ bias,
    const int* __restrict__ bucket,
    const int* __restrict__ ecnt,
    const int* __restrict__ table,
    void* __restrict__ Out)
{
    const int bid = blockIdx.x;
    const int xcd = bid & 7;
    const int q = bid >> 3;
    const int x = q % NX;
    const int yk = (q / NX) % (MAXTILES / 8);
    const int z = q / (NX * (MAXTILES / 8));
    const int y = xcd + 8 * yk;

    const int entry = table[y];
    if (entry < 0) return;
    const int e = entry >> 16;
    const int m0 = entry & 0xffff;
    const int cnt = ecnt[e];
    const int n0 = x * 128;
    const int kbase = (K / KS) * z;

    __shared__ __align__(16) __hip_bfloat16 Asm[128 * 64];  // 16 KB, row-major [128][64]
    __shared__ __align__(16) __hip_bfloat16 Bsm[128 * 64];  // 16 KB
    __shared__ int toks[128];

    const int tid = threadIdx.x;
    if (tid < 128) {
        int r = m0 + tid;
        toks[tid] = bucket[e * NTOK + (r < cnt ? r : cnt - 1)];
    }
    __syncthreads();

    const int wave = tid >> 6, lane = tid & 63;
    const int srow = lane >> 3;          // 0..7: row within 8-row staging group
    const int scol = (lane & 7) * 16;    // 0..112: byte offset within 128-B row chunk

    // Per-lane staging sources. A rows are token-gathered (4 separate pointers);
    // B rows are consecutive (1 pointer + compile-time offsets).
    const char* pA[4];
#pragma unroll
    for (int i = 0; i < 4; i++)
        pA[i] = (const char*)(A + (size_t)toks[wave * 32 + i * 8 + srow] * K + kbase) + scol;
    const char* pB = (const char*)(Bt + ((size_t)e * NN + n0 + wave * 32 + srow) * K + kbase) + scol;

    const int wm = wave & 1, wn = wave >> 1;
    const int r16 = lane & 15, kq16 = lane >> 4;

    f32x4 acc[4][4];
#pragma unroll
    for (int t = 0; t < 4; t++)
#pragma unroll
        for (int u = 0; u < 4; u++) acc[t][u] = (f32x4){0.f, 0.f, 0.f, 0.f};

    for (int k0 = 0; k0 < K / KS; k0 += 64) {
        // stage BK=64 tile: per wave 4 A-GLDS + 4 B-GLDS, each 8 rows x 128 B
#pragma unroll
        for (int i = 0; i < 4; i++) {
            GLDS(pA[i], (char*)Asm + (wave * 32 + i * 8) * 128 + lane * 16);
            GLDS(pB + (size_t)i * 8 * K * 2, (char*)Bsm + (wave * 32 + i * 8) * 128 + lane * 16);
            pA[i] += 128;
        }
        pB += 128;
        __syncthreads();

#pragma unroll
        for (int ksub = 0; ksub < 2; ksub++) {
            bf16x8 a[4], b[4];
#pragma unroll
            for (int t = 0; t < 4; t++)
                a[t] = *(const bf16x8*)((const char*)Asm +
                        (wm * 64 + t * 16 + r16) * 128 + kq16 * 16 + ksub * 64);
#pragma unroll
            for (int u = 0; u < 4; u++)
                b[u] = *(const bf16x8*)((const char*)Bsm +
                        (wn * 64 + u * 16 + r16) * 128 + kq16 * 16 + ksub * 64);
#pragma unroll
            for (int t = 0; t < 4; t++)
#pragma unroll
                for (int u = 0; u < 4; u++)
                    acc[t][u] = __builtin_amdgcn_mfma_f32_16x16x32_bf16(a[t], b[u], acc[t][u], 0, 0, 0);
        }
        __syncthreads();
    }

    const int quad = lane >> 4, l15 = lane & 15;
    float bv[4];
#pragma unroll
    for (int u = 0; u < 4; u++) {
        if (MODE == 0)
            bv[u] = bias[(size_t)e * NN + n0 + wn * 64 + u * 16 + l15];
        else
            bv[u] = (z == 0) ? bias[(size_t)e * NN + n0 + wn * 64 + u * 16 + l15] : 0.0f;
    }
#pragma unroll
    for (int t = 0; t < 4; t++) {
#pragma unroll
        for (int rr = 0; rr < 4; rr++) {
            int row = wm * 64 + t * 16 + quad * 4 + rr;
            if (m0 + row < cnt) {
                int tok = toks[row];
#pragma unroll
                for (int u = 0; u < 4; u++) {
                    int col = n0 + wn * 64 + u * 16 + l15;
                    float v = acc[t][u][rr] + bv[u];
                    if (MODE == 0) {
                        v = fmaxf(v, 0.0f);
                        ((__hip_bfloat16*)Out)[(size_t)tok * NN + col] = __float2bfloat16(v);
                    } else {
                        unsafeAtomicAdd(&((float*)Out)[(size_t)tok * NN + col], v);
                    }
                }
            }
        }
    }
}

__global__ __launch_bounds__(256, 4) void gemm_ffn1(
    const __hip_bfloat16* __restrict__ A, const __hip_bfloat16* __restrict__ Bt,
    const float* __restrict__ bias, const int* __restrict__ bucket,
    const int* __restrict__ ecnt, const int* __restrict__ table, void* __restrict__ Out)
{
    gemm_body<0, DDIM, FDIM, 1, FDIM / 128>(A, Bt, bias, bucket, ecnt, table, Out);
}

__global__ __launch_bounds__(256, 4) void gemm_ffn2(
    const __hip_bfloat16* __restrict__ A, const __hip_bfloat16* __restrict__ Bt,
    const float* __restrict__ bias, const int* __restrict__ bucket,
    const int* __restrict__ ecnt, const int* __restrict__ table, void* __restrict__ Out)
{
    gemm_body<1, FDIM, DDIM, 4, DDIM / 128>(A, Bt, bias, bucket, ecnt, table, Out);
}

extern "C" void kernel_launch(void* const* d_in, const int* in_sizes, int n_in,
                              void* d_out, int out_size, void* d_ws, size_t ws_size,
                              hipStream_t stream) {
    const float* x        = (const float*)d_in[0];
    const float* w_switch = (const float*)d_in[1];
    const float* b_switch = (const float*)d_in[2];
    const float* w1       = (const float*)d_in[3];
    const float* b1       = (const float*)d_in[4];
    const float* w2       = (const float*)d_in[5];
    const float* b2       = (const float*)d_in[6];

    float* out = (float*)d_out;
    float* out_tail = out + (size_t)NTOK * DDIM;

    char* ws = (char*)d_ws;
    __hip_bfloat16* xs = (__hip_bfloat16*)(ws);                        // 8 MB
    __hip_bfloat16* h  = (__hip_bfloat16*)(ws + 8388608ull);           // 32 MB
    __hip_bfloat16* wt = (__hip_bfloat16*)(ws + 41943040ull);          // 64 MB (shared w1t/w2t)
    int* bucket        = (int*)(ws + 109051904ull);                    // 128 KB
    int* amax_arr      = (int*)(ws + 109182976ull);                    // 16 KB
    float* partial     = (float*)(ws + 109199360ull);                  // 16 KB
    int* ecnt          = (int*)(ws + 109215744ull);                    // 32 B
    int* table         = (int*)(ws + 109215776ull);                    // 160 B

    // zero the accumulation target (replaces init_out; b2 bias folded into z==0 GEMM blocks)
    hipMemsetAsync(out, 0, (size_t)NTOK * DDIM * sizeof(float), stream);

    hipLaunchKernelGGL(route_kernel, dim3(256), dim3(256), 0, stream,
                       x, w_switch, b_switch, xs, amax_arr, partial);
    hipLaunchKernelGGL(bucket_kernel, dim3(NEXP), dim3(1024), 0, stream,
                       amax_arr, bucket, ecnt);
    hipLaunchKernelGGL(finalize_table_kernel, dim3(1), dim3(256), 0, stream,
                       partial, ecnt, out_tail, table);

    // w1 [E,1024,4096] -> w1t [E,4096,1024]
    hipLaunchKernelGGL((transpose_kernel<DDIM, FDIM>), dim3(FDIM / 64, DDIM / 64, NEXP),
                       dim3(256), 0, stream, w1, wt);
    hipLaunchKernelGGL(gemm_ffn1, dim3((FDIM / 128) * MAXTILES), dim3(256), 0, stream,
                       xs, wt, b1, bucket, ecnt, table, (void*)h);

    // w2 [E,4096,1024] -> w2t [E,1024,4096]  (reuses wt after gemm1)
    hipLaunchKernelGGL((transpose_kernel<FDIM, DDIM>), dim3(DDIM / 64, FDIM / 64, NEXP),
                       dim3(256), 0, stream, w2, wt);
    hipLaunchKernelGGL(gemm_ffn2, dim3((DDIM / 128) * MAXTILES * 4), dim3(256), 0, stream,
                       h, wt, b2, bucket, ecnt, table, (void*)out);
}

// Round 6
// 481.888 us; speedup vs baseline: 1.1539x; 1.0071x over previous
//
#include <hip/hip_runtime.h>
#include <hip/hip_bf16.h>

#define NTOK 4096
#define DDIM 1024
#define NEXP 8
#define FDIM 4096
#define MAXTILES 40

typedef __attribute__((ext_vector_type(4))) float f32x4;
typedef __attribute__((ext_vector_type(8))) short bf16x8;
typedef __attribute__((ext_vector_type(8))) unsigned short u16x8;

#define GLDS(g, l) __builtin_amdgcn_global_load_lds( \
    (const __attribute__((address_space(1))) unsigned int*)(g), \
    (__attribute__((address_space(3))) unsigned int*)(l), 16, 0, 0)

// ---------------- route: no global atomics. Writes xs (bf16), amax[], partial[256][16] ----
__global__ __launch_bounds__(256) void route_kernel(
    const float* __restrict__ x,         // [NTOK, D]
    const float* __restrict__ w_switch,  // [D, E]
    const float* __restrict__ b_switch,  // [E]
    __hip_bfloat16* __restrict__ xs,     // [NTOK, D]
    int* __restrict__ amax_arr,          // [NTOK]
    float* __restrict__ partial)         // [256][16]: 0..7 prob sums, 8..15 counts
{
    const int tid = threadIdx.x;
    const int wave = tid >> 6, lane = tid & 63;
    __shared__ float pr[4][16];

    float wacc[16];
#pragma unroll
    for (int j = 0; j < 16; j++) wacc[j] = 0.0f;

    for (int i = 0; i < 4; i++) {
        const int n = blockIdx.x * 16 + wave * 4 + i;
        const float4* xr = (const float4*)(x + (size_t)n * DDIM);
        float4 xv[4];
#pragma unroll
        for (int j = 0; j < 4; j++) xv[j] = xr[lane + j * 64];

        float acc[NEXP];
#pragma unroll
        for (int e = 0; e < NEXP; e++) acc[e] = 0.0f;
#pragma unroll
        for (int j = 0; j < 4; j++) {
            const int dbase = (lane + j * 64) * 4;
#pragma unroll
            for (int c = 0; c < 4; c++) {
                const float4* wr = (const float4*)(w_switch + (size_t)(dbase + c) * NEXP);
                float4 w0 = wr[0], w1 = wr[1];
                float xvc = ((const float*)&xv[j])[c];
                acc[0] += xvc * w0.x; acc[1] += xvc * w0.y;
                acc[2] += xvc * w0.z; acc[3] += xvc * w0.w;
                acc[4] += xvc * w1.x; acc[5] += xvc * w1.y;
                acc[6] += xvc * w1.z; acc[7] += xvc * w1.w;
            }
        }
#pragma unroll
        for (int e = 0; e < NEXP; e++) {
            float v = acc[e];
#pragma unroll
            for (int off = 32; off > 0; off >>= 1) v += __shfl_xor(v, off, 64);
            acc[e] = v;
        }
        float mx = -1e30f;
#pragma unroll
        for (int e = 0; e < NEXP; e++) {
            acc[e] += b_switch[e];
            mx = fmaxf(mx, acc[e]);
        }
        float sum = 0.0f;
#pragma unroll
        for (int e = 0; e < NEXP; e++) { acc[e] = __expf(acc[e] - mx); sum += acc[e]; }
        float inv = 1.0f / sum;
        float pmax = -1.0f; int amax = 0;
#pragma unroll
        for (int e = 0; e < NEXP; e++) {
            float p = acc[e] * inv;
            acc[e] = p;
            if (p > pmax) { pmax = p; amax = e; }
        }
#pragma unroll
        for (int e = 0; e < NEXP; e++) {
            wacc[e] += acc[e];
            wacc[8 + e] += (amax == e) ? 1.0f : 0.0f;
        }
        if (lane == 0) amax_arr[n] = amax;
#pragma unroll
        for (int j = 0; j < 4; j++) {
            ushort4 pk;
            __hip_bfloat16* pp = (__hip_bfloat16*)&pk;
            pp[0] = __float2bfloat16(xv[j].x * pmax);
            pp[1] = __float2bfloat16(xv[j].y * pmax);
            pp[2] = __float2bfloat16(xv[j].z * pmax);
            pp[3] = __float2bfloat16(xv[j].w * pmax);
            *(ushort4*)(xs + (size_t)n * DDIM + (lane + j * 64) * 4) = pk;
        }
    }
    if (lane == 0) {
#pragma unroll
        for (int j = 0; j < 16; j++) pr[wave][j] = wacc[j];
    }
    __syncthreads();
    if (tid < 16)
        partial[blockIdx.x * 16 + tid] = pr[0][tid] + pr[1][tid] + pr[2][tid] + pr[3][tid];
}

// ---------------- bucket: per-expert token lists, ballot-aggregated, LDS counter ----------
__global__ __launch_bounds__(1024) void bucket_kernel(
    const int* __restrict__ amax_arr, int* __restrict__ bucket, int* __restrict__ ecnt)
{
    const int e = blockIdx.x;
    __shared__ int ctr;
    if (threadIdx.x == 0) ctr = 0;
    __syncthreads();
    const int lane = threadIdx.x & 63;
    for (int c = 0; c < NTOK; c += 1024) {
        int t = c + threadIdx.x;
        bool my = (amax_arr[t] == e);
        unsigned long long mask = __ballot(my);
        int cnt = __popcll(mask);
        int base = 0;
        if (lane == 0 && cnt) base = atomicAdd(&ctr, cnt);
        base = __shfl(base, 0, 64);
        if (my) {
            int rank = __popcll(mask & ((1ull << lane) - 1ull));
            bucket[e * NTOK + base + rank] = t;
        }
    }
    __syncthreads();
    if (threadIdx.x == 0) ecnt[e] = ctr;
}

// ---------------- finalize + m-tile table ----------------
__global__ __launch_bounds__(256) void finalize_table_kernel(
    const float* __restrict__ partial, const int* __restrict__ ecnt,
    float* __restrict__ out_tail, int* __restrict__ table)
{
    __shared__ float red[16][16];
    const int j = threadIdx.x & 15, g = threadIdx.x >> 4;
    float s = 0.0f;
    for (int k = 0; k < 16; k++) s += partial[(size_t)(g + k * 16) * 16 + j];
    red[g][j] = s;
    __syncthreads();
    if (threadIdx.x < 16) {
        float t = 0.0f;
        for (int k = 0; k < 16; k++) t += red[k][threadIdx.x];
        int dst = (threadIdx.x < 8) ? (8 + threadIdx.x) : (threadIdx.x - 8);
        out_tail[dst] = t;
    }
    if (threadIdx.x == 16) out_tail[16] = 0.0f;  // n_dropped
    if (threadIdx.x == 0) {
        int idx = 0;
        for (int e = 0; e < NEXP; e++) {
            int cnt = ecnt[e];
            for (int m0 = 0; m0 < cnt; m0 += 128) table[idx++] = (e << 16) | m0;
        }
        for (; idx < MAXTILES; idx++) table[idx] = -1;
    }
}

// ---------------- transpose+convert: fp32 [E,R,C] -> bf16 [E,C,R] ----------------
template <int R, int C>
__global__ __launch_bounds__(256) void transpose_kernel(
    const float* __restrict__ in, __hip_bfloat16* __restrict__ outp)
{
    const int e = blockIdx.z;
    const int r0 = blockIdx.y * 64, c0 = blockIdx.x * 64;
    __shared__ __hip_bfloat16 t[64 * 65];
    const int tid = threadIdx.x;
    const int ri = tid >> 4, c4 = (tid & 15) * 4;
    const float* src = in + ((size_t)e * R + r0) * C + c0;
#pragma unroll
    for (int rr = 0; rr < 4; rr++) {
        int r = ri + rr * 16;
        float4 v = *(const float4*)(src + (size_t)r * C + c4);
        t[r * 65 + c4 + 0] = __float2bfloat16(v.x);
        t[r * 65 + c4 + 1] = __float2bfloat16(v.y);
        t[r * 65 + c4 + 2] = __float2bfloat16(v.z);
        t[r * 65 + c4 + 3] = __float2bfloat16(v.w);
    }
    __syncthreads();
    const int co = tid >> 2, m = tid & 3;
    u16x8 v0, v1;
#pragma unroll
    for (int idx = 0; idx < 8; idx++)
        ((unsigned short*)&v0)[idx] = *(const unsigned short*)&t[(m * 16 + idx) * 65 + co];
#pragma unroll
    for (int idx = 0; idx < 8; idx++)
        ((unsigned short*)&v1)[idx] = *(const unsigned short*)&t[(m * 16 + idx + 8) * 65 + co];
    __hip_bfloat16* dst = outp + ((size_t)e * C + c0 + co) * R + r0 + m * 16;
    *(u16x8*)(dst) = v0;
    *(u16x8*)(dst + 8) = v1;
}

// ---------------- grouped GEMM body: 128x128 tile, BK=64, single-buffer, T2 XOR-swizzle ---
// LDS tile [128][64] bf16 = 128 B rows. Unswizzled ds_read_b128 fragment reads are a 16-way
// bank conflict (all r16 lanes hit the same 16B column slot). Fix per rule #21 (both-sides):
//   - global_load_lds dest stays LINEAR (HW requires it); the SOURCE column is pre-swizzled:
//     physical slot s of row r holds logical slot s ^ (r&7)  (source col = (l&7 ^ l>>3)*16)
//   - ds_read applies the same XOR: slot = (kq16 + ksub*4) ^ (r16&7)
// After swizzle each ds_read_b128 hits 8 slots x 8 lanes = the b128 floor, conflict-free.
// XCD-affine decode (T1): xcd = bid&7 pins the m-tile; x sweeps fastest within the XCD.
// MODE 0: h = bf16(relu(acc + bias)), KS=1.
// MODE 1: unsafeAtomicAdd fp32 into zeroed out; z==0 block also adds bias.
template <int MODE, int K, int NN, int KS, int NX>
__device__ __forceinline__ void gemm_body(
    const __hip_bfloat16* __restrict__ A,
    const __hip_bfloat16* __restrict__ Bt,
    const float* __restrict__ bias,
    const int* __restrict__ bucket,
    const int* __restrict__ ecnt,
    const int* __restrict__ table,
    void* __restrict__ Out)
{
    const int bid = blockIdx.x;
    const int xcd = bid & 7;
    const int q = bid >> 3;
    const int x = q % NX;
    const int yk = (q / NX) % (MAXTILES / 8);
    const int z = q / (NX * (MAXTILES / 8));
    const int y = xcd + 8 * yk;

    const int entry = table[y];
    if (entry < 0) return;
    const int e = entry >> 16;
    const int m0 = entry & 0xffff;
    const int cnt = ecnt[e];
    const int n0 = x * 128;
    const int kbase = (K / KS) * z;

    __shared__ __align__(16) __hip_bfloat16 Asm[128 * 64];  // 16 KB, row-major [128][64]
    __shared__ __align__(16) __hip_bfloat16 Bsm[128 * 64];  // 16 KB
    __shared__ int toks[128];

    const int tid = threadIdx.x;
    if (tid < 128) {
        int r = m0 + tid;
        toks[tid] = bucket[e * NTOK + (r < cnt ? r : cnt - 1)];
    }
    __syncthreads();

    const int wave = tid >> 6, lane = tid & 63;
    const int srow = lane >> 3;                        // 0..7: row within 8-row staging group
    const int swzcol = ((lane & 7) ^ srow) * 16;       // pre-swizzled SOURCE byte column

    // Per-lane staging sources (pre-swizzled column). A rows are token-gathered;
    // B rows are consecutive (1 pointer + compile-time offsets).
    const char* pA[4];
#pragma unroll
    for (int i = 0; i < 4; i++)
        pA[i] = (const char*)(A + (size_t)toks[wave * 32 + i * 8 + srow] * K + kbase) + swzcol;
    const char* pB = (const char*)(Bt + ((size_t)e * NN + n0 + wave * 32 + srow) * K + kbase) + swzcol;

    const int wm = wave & 1, wn = wave >> 1;
    const int r16 = lane & 15, kq16 = lane >> 4;
    const int r7x = (r16 & 7) * 16;                    // XOR term for swizzled ds_read

    f32x4 acc[4][4];
#pragma unroll
    for (int t = 0; t < 4; t++)
#pragma unroll
        for (int u = 0; u < 4; u++) acc[t][u] = (f32x4){0.f, 0.f, 0.f, 0.f};

    for (int k0 = 0; k0 < K / KS; k0 += 64) {
        // stage BK=64 tile: per wave 4 A-GLDS + 4 B-GLDS, each 8 rows x 128 B (linear dest)
#pragma unroll
        for (int i = 0; i < 4; i++) {
            GLDS(pA[i], (char*)Asm + (wave * 32 + i * 8) * 128 + lane * 16);
            GLDS(pB + (size_t)i * 8 * K * 2, (char*)Bsm + (wave * 32 + i * 8) * 128 + lane * 16);
            pA[i] += 128;
        }
        pB += 128;
        __syncthreads();

#pragma unroll
        for (int ksub = 0; ksub < 2; ksub++) {
            const int slot = ((kq16 + ksub * 4) * 16) ^ r7x;  // swizzled column byte offset
            bf16x8 a[4], b[4];
#pragma unroll
            for (int t = 0; t < 4; t++)
                a[t] = *(const bf16x8*)((const char*)Asm +
                        (wm * 64 + t * 16 + r16) * 128 + slot);
#pragma unroll
            for (int u = 0; u < 4; u++)
                b[u] = *(const bf16x8*)((const char*)Bsm +
                        (wn * 64 + u * 16 + r16) * 128 + slot);
#pragma unroll
            for (int t = 0; t < 4; t++)
#pragma unroll
                for (int u = 0; u < 4; u++)
                    acc[t][u] = __builtin_amdgcn_mfma_f32_16x16x32_bf16(a[t], b[u], acc[t][u], 0, 0, 0);
        }
        __syncthreads();
    }

    const int quad = lane >> 4, l15 = lane & 15;
    float bv[4];
#pragma unroll
    for (int u = 0; u < 4; u++) {
        if (MODE == 0)
            bv[u] = bias[(size_t)e * NN + n0 + wn * 64 + u * 16 + l15];
        else
            bv[u] = (z == 0) ? bias[(size_t)e * NN + n0 + wn * 64 + u * 16 + l15] : 0.0f;
    }
#pragma unroll
    for (int t = 0; t < 4; t++) {
#pragma unroll
        for (int rr = 0; rr < 4; rr++) {
            int row = wm * 64 + t * 16 + quad * 4 + rr;
            if (m0 + row < cnt) {
                int tok = toks[row];
#pragma unroll
                for (int u = 0; u < 4; u++) {
                    int col = n0 + wn * 64 + u * 16 + l15;
                    float v = acc[t][u][rr] + bv[u];
                    if (MODE == 0) {
                        v = fmaxf(v, 0.0f);
                        ((__hip_bfloat16*)Out)[(size_t)tok * NN + col] = __float2bfloat16(v);
                    } else {
                        unsafeAtomicAdd(&((float*)Out)[(size_t)tok * NN + col], v);
                    }
                }
            }
        }
    }
}

__global__ __launch_bounds__(256, 4) void gemm_ffn1(
    const __hip_bfloat16* __restrict__ A, const __hip_bfloat16* __restrict__ Bt,
    const float* __restrict__ bias, const int* __restrict__ bucket,
    const int* __restrict__ ecnt, const int* __restrict__ table, void* __restrict__ Out)
{
    gemm_body<0, DDIM, FDIM, 1, FDIM / 128>(A, Bt, bias, bucket, ecnt, table, Out);
}

__global__ __launch_bounds__(256, 4) void gemm_ffn2(
    const __hip_bfloat16* __restrict__ A, const __hip_bfloat16* __restrict__ Bt,
    const float* __restrict__ bias, const int* __restrict__ bucket,
    const int* __restrict__ ecnt, const int* __restrict__ table, void* __restrict__ Out)
{
    gemm_body<1, FDIM, DDIM, 4, DDIM / 128>(A, Bt, bias, bucket, ecnt, table, Out);
}

extern "C" void kernel_launch(void* const* d_in, const int* in_sizes, int n_in,
                              void* d_out, int out_size, void* d_ws, size_t ws_size,
                              hipStream_t stream) {
    const float* x        = (const float*)d_in[0];
    const float* w_switch = (const float*)d_in[1];
    const float* b_switch = (const float*)d_in[2];
    const float* w1       = (const float*)d_in[3];
    const float* b1       = (const float*)d_in[4];
    const float* w2       = (const float*)d_in[5];
    const float* b2       = (const float*)d_in[6];

    float* out = (float*)d_out;
    float* out_tail = out + (size_t)NTOK * DDIM;

    char* ws = (char*)d_ws;
    __hip_bfloat16* xs = (__hip_bfloat16*)(ws);                        // 8 MB
    __hip_bfloat16* h  = (__hip_bfloat16*)(ws + 8388608ull);           // 32 MB
    __hip_bfloat16* wt = (__hip_bfloat16*)(ws + 41943040ull);          // 64 MB (shared w1t/w2t)
    int* bucket        = (int*)(ws + 109051904ull);                    // 128 KB
    int* amax_arr      = (int*)(ws + 109182976ull);                    // 16 KB
    float* partial     = (float*)(ws + 109199360ull);                  // 16 KB
    int* ecnt          = (int*)(ws + 109215744ull);                    // 32 B
    int* table         = (int*)(ws + 109215776ull);                    // 160 B

    // zero the accumulation target (replaces init_out; b2 bias folded into z==0 GEMM blocks)
    hipMemsetAsync(out, 0, (size_t)NTOK * DDIM * sizeof(float), stream);

    hipLaunchKernelGGL(route_kernel, dim3(256), dim3(256), 0, stream,
                       x, w_switch, b_switch, xs, amax_arr, partial);
    hipLaunchKernelGGL(bucket_kernel, dim3(NEXP), dim3(1024), 0, stream,
                       amax_arr, bucket, ecnt);
    hipLaunchKernelGGL(finalize_table_kernel, dim3(1), dim3(256), 0, stream,
                       partial, ecnt, out_tail, table);

    // w1 [E,1024,4096] -> w1t [E,4096,1024]
    hipLaunchKernelGGL((transpose_kernel<DDIM, FDIM>), dim3(FDIM / 64, DDIM / 64, NEXP),
                       dim3(256), 0, stream, w1, wt);
    hipLaunchKernelGGL(gemm_ffn1, dim3((FDIM / 128) * MAXTILES), dim3(256), 0, stream,
                       xs, wt, b1, bucket, ecnt, table, (void*)h);

    // w2 [E,4096,1024] -> w2t [E,1024,4096]  (reuses wt after gemm1)
    hipLaunchKernelGGL((transpose_kernel<FDIM, DDIM>), dim3(DDIM / 64, FDIM / 64, NEXP),
                       dim3(256), 0, stream, w2, wt);
    hipLaunchKernelGGL(gemm_ffn2, dim3((DDIM / 128) * MAXTILES * 4), dim3(256), 0, stream,
                       h, wt, b2, bucket, ecnt, table, (void*)out);
}

// Round 7
// 480.846 us; speedup vs baseline: 1.1564x; 1.0022x over previous
//
#include <hip/hip_runtime.h>
#include <hip/hip_bf16.h>

#define NTOK 4096
#define DDIM 1024
#define NEXP 8
#define FDIM 4096
#define MAXTILES 40

typedef __attribute__((ext_vector_type(4))) float f32x4;
typedef __attribute__((ext_vector_type(8))) short bf16x8;

#define GLDS(g, l) __builtin_amdgcn_global_load_lds( \
    (const __attribute__((address_space(1))) unsigned int*)(g), \
    (__attribute__((address_space(3))) unsigned int*)(l), 16, 0, 0)

// ---------------- route: no global atomics. Writes xs (bf16), amax[], partial[256][16] ----
__global__ __launch_bounds__(256) void route_kernel(
    const float* __restrict__ x,         // [NTOK, D]
    const float* __restrict__ w_switch,  // [D, E]
    const float* __restrict__ b_switch,  // [E]
    __hip_bfloat16* __restrict__ xs,     // [NTOK, D]
    int* __restrict__ amax_arr,          // [NTOK]
    float* __restrict__ partial)         // [256][16]: 0..7 prob sums, 8..15 counts
{
    const int tid = threadIdx.x;
    const int wave = tid >> 6, lane = tid & 63;
    __shared__ float pr[4][16];

    float wacc[16];
#pragma unroll
    for (int j = 0; j < 16; j++) wacc[j] = 0.0f;

    for (int i = 0; i < 4; i++) {
        const int n = blockIdx.x * 16 + wave * 4 + i;
        const float4* xr = (const float4*)(x + (size_t)n * DDIM);
        float4 xv[4];
#pragma unroll
        for (int j = 0; j < 4; j++) xv[j] = xr[lane + j * 64];

        float acc[NEXP];
#pragma unroll
        for (int e = 0; e < NEXP; e++) acc[e] = 0.0f;
#pragma unroll
        for (int j = 0; j < 4; j++) {
            const int dbase = (lane + j * 64) * 4;
#pragma unroll
            for (int c = 0; c < 4; c++) {
                const float4* wr = (const float4*)(w_switch + (size_t)(dbase + c) * NEXP);
                float4 w0 = wr[0], w1 = wr[1];
                float xvc = ((const float*)&xv[j])[c];
                acc[0] += xvc * w0.x; acc[1] += xvc * w0.y;
                acc[2] += xvc * w0.z; acc[3] += xvc * w0.w;
                acc[4] += xvc * w1.x; acc[5] += xvc * w1.y;
                acc[6] += xvc * w1.z; acc[7] += xvc * w1.w;
            }
        }
#pragma unroll
        for (int e = 0; e < NEXP; e++) {
            float v = acc[e];
#pragma unroll
            for (int off = 32; off > 0; off >>= 1) v += __shfl_xor(v, off, 64);
            acc[e] = v;
        }
        float mx = -1e30f;
#pragma unroll
        for (int e = 0; e < NEXP; e++) {
            acc[e] += b_switch[e];
            mx = fmaxf(mx, acc[e]);
        }
        float sum = 0.0f;
#pragma unroll
        for (int e = 0; e < NEXP; e++) { acc[e] = __expf(acc[e] - mx); sum += acc[e]; }
        float inv = 1.0f / sum;
        float pmax = -1.0f; int amax = 0;
#pragma unroll
        for (int e = 0; e < NEXP; e++) {
            float p = acc[e] * inv;
            acc[e] = p;
            if (p > pmax) { pmax = p; amax = e; }
        }
#pragma unroll
        for (int e = 0; e < NEXP; e++) {
            wacc[e] += acc[e];
            wacc[8 + e] += (amax == e) ? 1.0f : 0.0f;
        }
        if (lane == 0) amax_arr[n] = amax;
#pragma unroll
        for (int j = 0; j < 4; j++) {
            ushort4 pk;
            __hip_bfloat16* pp = (__hip_bfloat16*)&pk;
            pp[0] = __float2bfloat16(xv[j].x * pmax);
            pp[1] = __float2bfloat16(xv[j].y * pmax);
            pp[2] = __float2bfloat16(xv[j].z * pmax);
            pp[3] = __float2bfloat16(xv[j].w * pmax);
            *(ushort4*)(xs + (size_t)n * DDIM + (lane + j * 64) * 4) = pk;
        }
    }
    if (lane == 0) {
#pragma unroll
        for (int j = 0; j < 16; j++) pr[wave][j] = wacc[j];
    }
    __syncthreads();
    if (tid < 16)
        partial[blockIdx.x * 16 + tid] = pr[0][tid] + pr[1][tid] + pr[2][tid] + pr[3][tid];
}

// ---------------- bucket + finalize merged: one block, ecnt stays in LDS ----------------
__global__ __launch_bounds__(1024) void bucket_finalize_kernel(
    const int* __restrict__ amax_arr, const float* __restrict__ partial,
    int* __restrict__ bucket, int* __restrict__ ecnt,
    float* __restrict__ out_tail, int* __restrict__ table)
{
    __shared__ int ctr[NEXP];
    __shared__ float red[16][16];
    if (threadIdx.x < NEXP) ctr[threadIdx.x] = 0;
    __syncthreads();
    const int lane = threadIdx.x & 63;
    for (int c = 0; c < NTOK; c += 1024) {
        int t = c + threadIdx.x;
        int a = amax_arr[t];
#pragma unroll
        for (int e = 0; e < NEXP; e++) {
            bool my = (a == e);
            unsigned long long mask = __ballot(my);
            int cnt = __popcll(mask);
            int base = 0;
            if (lane == 0 && cnt) base = atomicAdd(&ctr[e], cnt);
            base = __shfl(base, 0, 64);
            if (my) {
                int rank = __popcll(mask & ((1ull << lane) - 1ull));
                bucket[e * NTOK + base + rank] = t;
            }
        }
    }
    // prob-sum reduction (first 256 threads)
    if (threadIdx.x < 256) {
        const int j = threadIdx.x & 15, g = threadIdx.x >> 4;
        float s = 0.0f;
        for (int k = 0; k < 16; k++) s += partial[(size_t)(g + k * 16) * 16 + j];
        red[g][j] = s;
    }
    __syncthreads();
    if (threadIdx.x < NEXP) ecnt[threadIdx.x] = ctr[threadIdx.x];
    if (threadIdx.x < 16) {
        float t2 = 0.0f;
        for (int k = 0; k < 16; k++) t2 += red[k][threadIdx.x];
        int dst = (threadIdx.x < 8) ? (8 + threadIdx.x) : (threadIdx.x - 8);
        out_tail[dst] = t2;
    }
    if (threadIdx.x == 16) out_tail[16] = 0.0f;  // n_dropped
    if (threadIdx.x == 0) {
        int idx = 0;
        for (int e = 0; e < NEXP; e++) {
            int cnt2 = ctr[e];
            for (int m0 = 0; m0 < cnt2; m0 += 128) table[idx++] = (e << 16) | m0;
        }
        for (; idx < MAXTILES; idx++) table[idx] = -1;
    }
}

// ---------------- transpose+convert v2: fp32 [E,R,C] -> bf16 [E,C,R] ----------------
// 128x128 tile / 256 threads. Phase 1: coalesced float4 loads -> cvt -> VECTOR ds_write_b64
// into bf16 LDS [128][128] (1-bit XOR swizzle balances banks). Phase 2: 8x ds_read_b128
// per thread (8x8 bf16 block), in-register 8x8 transpose via v_perm_b32, coalesced 16B
// stores (4x256B runs per instr). Replaces the old kernel's 48 scalar LDS ops/thread.
template <int R, int C>
__global__ __launch_bounds__(256) void transpose_kernel(
    const float* __restrict__ in, __hip_bfloat16* __restrict__ outp)
{
    const int e = blockIdx.z;
    const int r0 = blockIdx.y * 128, c0 = blockIdx.x * 128;
    __shared__ __align__(16) __hip_bfloat16 t[128 * 128];  // 32 KB
    const int tid = threadIdx.x;

    // phase 1: 16 float4 per thread, lane-linear so each wave covers 2 x 512B runs
    const float* src = in + ((size_t)e * R + r0) * C + c0;
#pragma unroll
    for (int k = 0; k < 16; k++) {
        const int id = k * 256 + tid;          // 0..4095 float4 chunks
        const int row = id >> 5, colq = id & 31;
        float4 v = *(const float4*)(src + (size_t)row * C + colq * 4);
        ushort4 pk;
        __hip_bfloat16* pp = (__hip_bfloat16*)&pk;
        pp[0] = __float2bfloat16(v.x); pp[1] = __float2bfloat16(v.y);
        pp[2] = __float2bfloat16(v.z); pp[3] = __float2bfloat16(v.w);
        const int b = (row * 256 + colq * 8) ^ (((row >> 3) & 1) << 6);
        *(ushort4*)((char*)t + b) = pk;
    }
    __syncthreads();

    // phase 2: thread (rb, cb) owns input rows rb*8..+8, cols cb*8..+8
    const int rb = tid & 15, cb = tid >> 4;
    unsigned v[8][4];
#pragma unroll
    for (int i = 0; i < 8; i++) {
        const int row = rb * 8 + i;
        const int b = (row * 256 + cb * 16) ^ ((rb & 1) << 6);
        *(uint4*)v[i] = *(const uint4*)((const char*)t + b);
    }
    __hip_bfloat16* dst = outp + ((size_t)e * C + c0 + cb * 8) * R + r0 + rb * 8;
#pragma unroll
    for (int j = 0; j < 8; j++) {
        const unsigned sel = (j & 1) ? 0x07060302u : 0x05040100u;
        unsigned o[4];
#pragma unroll
        for (int w = 0; w < 4; w++)
            o[w] = __builtin_amdgcn_perm(v[2 * w + 1][j >> 1], v[2 * w][j >> 1], sel);
        *(uint4*)(dst + (size_t)j * R) = *(uint4*)o;
    }
}

// ---------------- grouped GEMM body: 128x128 tile, BK=64, single-buffer, T2 XOR-swizzle ---
// (unchanged from R6 — proven state: 0 bank conflicts, occupancy 29%)
template <int MODE, int K, int NN, int KS, int NX>
__device__ __forceinline__ void gemm_body(
    const __hip_bfloat16* __restrict__ A,
    const __hip_bfloat16* __restrict__ Bt,
    const float* __restrict__ bias,
    const int* __restrict__ bucket,
    const int* __restrict__ ecnt,
    const int* __restrict__ table,
    void* __restrict__ Out)
{
    const int bid = blockIdx.x;
    const int xcd = bid & 7;
    const int q = bid >> 3;
    const int x = q % NX;
    const int yk = (q / NX) % (MAXTILES / 8);
    const int z = q / (NX * (MAXTILES / 8));
    const int y = xcd + 8 * yk;

    const int entry = table[y];
    if (entry < 0) return;
    const int e = entry >> 16;
    const int m0 = entry & 0xffff;
    const int cnt = ecnt[e];
    const int n0 = x * 128;
    const int kbase = (K / KS) * z;

    __shared__ __align__(16) __hip_bfloat16 Asm[128 * 64];  // 16 KB, row-major [128][64]
    __shared__ __align__(16) __hip_bfloat16 Bsm[128 * 64];  // 16 KB
    __shared__ int toks[128];

    const int tid = threadIdx.x;
    if (tid < 128) {
        int r = m0 + tid;
        toks[tid] = bucket[e * NTOK + (r < cnt ? r : cnt - 1)];
    }
    __syncthreads();

    const int wave = tid >> 6, lane = tid & 63;
    const int srow = lane >> 3;                        // 0..7: row within 8-row staging group
    const int swzcol = ((lane & 7) ^ srow) * 16;       // pre-swizzled SOURCE byte column

    const char* pA[4];
#pragma unroll
    for (int i = 0; i < 4; i++)
        pA[i] = (const char*)(A + (size_t)toks[wave * 32 + i * 8 + srow] * K + kbase) + swzcol;
    const char* pB = (const char*)(Bt + ((size_t)e * NN + n0 + wave * 32 + srow) * K + kbase) + swzcol;

    const int wm = wave & 1, wn = wave >> 1;
    const int r16 = lane & 15, kq16 = lane >> 4;
    const int r7x = (r16 & 7) * 16;                    // XOR term for swizzled ds_read

    f32x4 acc[4][4];
#pragma unroll
    for (int t = 0; t < 4; t++)
#pragma unroll
        for (int u = 0; u < 4; u++) acc[t][u] = (f32x4){0.f, 0.f, 0.f, 0.f};

    for (int k0 = 0; k0 < K / KS; k0 += 64) {
#pragma unroll
        for (int i = 0; i < 4; i++) {
            GLDS(pA[i], (char*)Asm + (wave * 32 + i * 8) * 128 + lane * 16);
            GLDS(pB + (size_t)i * 8 * K * 2, (char*)Bsm + (wave * 32 + i * 8) * 128 + lane * 16);
            pA[i] += 128;
        }
        pB += 128;
        __syncthreads();

#pragma unroll
        for (int ksub = 0; ksub < 2; ksub++) {
            const int slot = ((kq16 + ksub * 4) * 16) ^ r7x;  // swizzled column byte offset
            bf16x8 a[4], b[4];
#pragma unroll
            for (int t = 0; t < 4; t++)
                a[t] = *(const bf16x8*)((const char*)Asm +
                        (wm * 64 + t * 16 + r16) * 128 + slot);
#pragma unroll
            for (int u = 0; u < 4; u++)
                b[u] = *(const bf16x8*)((const char*)Bsm +
                        (wn * 64 + u * 16 + r16) * 128 + slot);
#pragma unroll
            for (int t = 0; t < 4; t++)
#pragma unroll
                for (int u = 0; u < 4; u++)
                    acc[t][u] = __builtin_amdgcn_mfma_f32_16x16x32_bf16(a[t], b[u], acc[t][u], 0, 0, 0);
        }
        __syncthreads();
    }

    const int quad = lane >> 4, l15 = lane & 15;
    float bv[4];
#pragma unroll
    for (int u = 0; u < 4; u++) {
        if (MODE == 0)
            bv[u] = bias[(size_t)e * NN + n0 + wn * 64 + u * 16 + l15];
        else
            bv[u] = (z == 0) ? bias[(size_t)e * NN + n0 + wn * 64 + u * 16 + l15] : 0.0f;
    }
#pragma unroll
    for (int t = 0; t < 4; t++) {
#pragma unroll
        for (int rr = 0; rr < 4; rr++) {
            int row = wm * 64 + t * 16 + quad * 4 + rr;
            if (m0 + row < cnt) {
                int tok = toks[row];
#pragma unroll
                for (int u = 0; u < 4; u++) {
                    int col = n0 + wn * 64 + u * 16 + l15;
                    float v = acc[t][u][rr] + bv[u];
                    if (MODE == 0) {
                        v = fmaxf(v, 0.0f);
                        ((__hip_bfloat16*)Out)[(size_t)tok * NN + col] = __float2bfloat16(v);
                    } else {
                        unsafeAtomicAdd(&((float*)Out)[(size_t)tok * NN + col], v);
                    }
                }
            }
        }
    }
}

__global__ __launch_bounds__(256, 4) void gemm_ffn1(
    const __hip_bfloat16* __restrict__ A, const __hip_bfloat16* __restrict__ Bt,
    const float* __restrict__ bias, const int* __restrict__ bucket,
    const int* __restrict__ ecnt, const int* __restrict__ table, void* __restrict__ Out)
{
    gemm_body<0, DDIM, FDIM, 1, FDIM / 128>(A, Bt, bias, bucket, ecnt, table, Out);
}

__global__ __launch_bounds__(256, 4) void gemm_ffn2(
    const __hip_bfloat16* __restrict__ A, const __hip_bfloat16* __restrict__ Bt,
    const float* __restrict__ bias, const int* __restrict__ bucket,
    const int* __restrict__ ecnt, const int* __restrict__ table, void* __restrict__ Out)
{
    gemm_body<1, FDIM, DDIM, 4, DDIM / 128>(A, Bt, bias, bucket, ecnt, table, Out);
}

extern "C" void kernel_launch(void* const* d_in, const int* in_sizes, int n_in,
                              void* d_out, int out_size, void* d_ws, size_t ws_size,
                              hipStream_t stream) {
    const float* x        = (const float*)d_in[0];
    const float* w_switch = (const float*)d_in[1];
    const float* b_switch = (const float*)d_in[2];
    const float* w1       = (const float*)d_in[3];
    const float* b1       = (const float*)d_in[4];
    const float* w2       = (const float*)d_in[5];
    const float* b2       = (const float*)d_in[6];

    float* out = (float*)d_out;
    float* out_tail = out + (size_t)NTOK * DDIM;

    char* ws = (char*)d_ws;
    __hip_bfloat16* xs = (__hip_bfloat16*)(ws);                        // 8 MB
    __hip_bfloat16* h  = (__hip_bfloat16*)(ws + 8388608ull);           // 32 MB
    __hip_bfloat16* wt = (__hip_bfloat16*)(ws + 41943040ull);          // 64 MB (shared w1t/w2t)
    int* bucket        = (int*)(ws + 109051904ull);                    // 128 KB
    int* amax_arr      = (int*)(ws + 109182976ull);                    // 16 KB
    float* partial     = (float*)(ws + 109199360ull);                  // 16 KB
    int* ecnt          = (int*)(ws + 109215744ull);                    // 32 B
    int* table         = (int*)(ws + 109215776ull);                    // 160 B

    // zero the accumulation target (b2 bias folded into z==0 GEMM blocks)
    hipMemsetAsync(out, 0, (size_t)NTOK * DDIM * sizeof(float), stream);

    hipLaunchKernelGGL(route_kernel, dim3(256), dim3(256), 0, stream,
                       x, w_switch, b_switch, xs, amax_arr, partial);
    hipLaunchKernelGGL(bucket_finalize_kernel, dim3(1), dim3(1024), 0, stream,
                       amax_arr, partial, bucket, ecnt, out_tail, table);

    // w1 [E,1024,4096] -> w1t [E,4096,1024]
    hipLaunchKernelGGL((transpose_kernel<DDIM, FDIM>), dim3(FDIM / 128, DDIM / 128, NEXP),
                       dim3(256), 0, stream, w1, wt);
    hipLaunchKernelGGL(gemm_ffn1, dim3((FDIM / 128) * MAXTILES), dim3(256), 0, stream,
                       xs, wt, b1, bucket, ecnt, table, (void*)h);

    // w2 [E,4096,1024] -> w2t [E,1024,4096]  (reuses wt after gemm1)
    hipLaunchKernelGGL((transpose_kernel<FDIM, DDIM>), dim3(DDIM / 128, FDIM / 128, NEXP),
                       dim3(256), 0, stream, w2, wt);
    hipLaunchKernelGGL(gemm_ffn2, dim3((DDIM / 128) * MAXTILES * 4), dim3(256), 0, stream,
                       h, wt, b2, bucket, ecnt, table, (void*)out);
}